// Round 2
// baseline (3649.030 us; speedup 1.0000x reference)
//
#include <hip/hip_runtime.h>
#include <cstdint>
#include <cstddef>

#define TOKENS 131072      // B*T = 512*256
#define B_BATCH 512
#define T_SEQ 256
#define C_DIM 512
#define H_HEADS 4
#define HS_DIM 128
#define FF_DIM 2048
#define EPS_RMS 1e-8f
#define SM_SCALE 0.044194173824159216f   // 512^-0.5

typedef short bf16x8 __attribute__((ext_vector_type(8)));
typedef float f32x4 __attribute__((ext_vector_type(4)));
typedef unsigned short ushort_t;

__device__ __forceinline__ ushort_t f2bf(float f) {
    uint32_t u = __builtin_bit_cast(uint32_t, f);
    u += 0x7FFFu + ((u >> 16) & 1u);   // round-to-nearest-even
    return (ushort_t)(u >> 16);
}

__device__ __forceinline__ float gelu_exact(float v) {
    return 0.5f * v * (1.0f + erff(v * 0.70710678118654752f));
}

// ---------------------------------------------------------------------------
// Weight prep: fp32 -> bf16, transposed to N x K row-major
// ---------------------------------------------------------------------------
__global__ void prep_qkv(const float* __restrict__ Wq, const float* __restrict__ Wk,
                         const float* __restrict__ Wv, ushort_t* __restrict__ WqkvT) {
    int idx = blockIdx.x * 256 + threadIdx.x;       // over 1536*512
    if (idx >= 1536 * 512) return;
    int n = idx >> 9;
    int k = idx & 511;
    int h = (n & 511) >> 7;
    int d = n & 127;
    float v;
    size_t s = ((size_t)h * 512 + k) * 128 + d;     // (H,C,HS)
    if (n < 512)       v = Wq[s];
    else if (n < 1024) v = Wk[s];
    else               v = Wv[s];
    WqkvT[idx] = f2bf(v);
}

__global__ void prep_bias(const float* __restrict__ bk, float* __restrict__ bias1536) {
    int n = blockIdx.x * 256 + threadIdx.x;
    if (n >= 1536) return;
    bias1536[n] = (n >= 512 && n < 1024) ? bk[n - 512] : 0.0f;   // bk flat (H,HS)
}

__global__ void prep_proj(const float* __restrict__ Wproj, ushort_t* __restrict__ WprojT) {
    int idx = blockIdx.x * 256 + threadIdx.x;       // over 512*512
    if (idx >= 512 * 512) return;
    int n = idx >> 9, k = idx & 511;
    WprojT[idx] = f2bf(Wproj[(size_t)k * 512 + n]);
}

__global__ void prep_wi(const float* __restrict__ Wi, ushort_t* __restrict__ WiT) {
    int idx = blockIdx.x * 256 + threadIdx.x;       // over 2*2048*512
    if (idx >= 2 * 2048 * 512) return;
    int b = idx >> 20;
    int rem = idx & 1048575;
    int f = rem >> 9, c = rem & 511;                // WiT[b][f][c]
    WiT[idx] = f2bf(Wi[((size_t)b * 512 + c) * 2048 + f]);
}

__global__ void prep_wo(const float* __restrict__ Wo, ushort_t* __restrict__ WoT) {
    int idx = blockIdx.x * 256 + threadIdx.x;       // over 2*512*2048
    if (idx >= 2 * 512 * 2048) return;
    int b = idx >> 20;
    int rem = idx & 1048575;
    int c = rem >> 11, f = rem & 2047;              // WoT[b][c][f]
    WoT[idx] = f2bf(Wo[((size_t)b * 2048 + f) * 512 + c]);
}

// ---------------------------------------------------------------------------
// RMSNorm: one wave per token (512 floats, 8/lane)
// ---------------------------------------------------------------------------
template<int WRITE_F32>
__global__ __launch_bounds__(256) void rmsnorm_kernel(const float* __restrict__ in,
                                                      const float* __restrict__ wptr,
                                                      ushort_t* __restrict__ outb,
                                                      float* outf) {
    const int lane = threadIdx.x & 63;
    const int wave = threadIdx.x >> 6;
    const size_t token = (size_t)blockIdx.x * 4 + wave;
    const float* row = in + token * 512;
    float4 v0 = *(const float4*)(row + lane * 8);
    float4 v1 = *(const float4*)(row + lane * 8 + 4);
    float ss = v0.x*v0.x + v0.y*v0.y + v0.z*v0.z + v0.w*v0.w
             + v1.x*v1.x + v1.y*v1.y + v1.z*v1.z + v1.w*v1.w;
    #pragma unroll
    for (int d = 32; d; d >>= 1) ss += __shfl_xor(ss, d);
    float scale = wptr[0] * rsqrtf(ss * (1.0f / 512.0f) + EPS_RMS);
    float vals[8] = {v0.x, v0.y, v0.z, v0.w, v1.x, v1.y, v1.z, v1.w};
    union { ushort_t us[8]; uint4 u4; } pk;
    #pragma unroll
    for (int i = 0; i < 8; i++) pk.us[i] = f2bf(vals[i] * scale);
    *(uint4*)(outb + token * 512 + lane * 8) = pk.u4;
    if (WRITE_F32) {
        float4 o0 = make_float4(v0.x*scale, v0.y*scale, v0.z*scale, v0.w*scale);
        float4 o1 = make_float4(v1.x*scale, v1.y*scale, v1.z*scale, v1.w*scale);
        *(float4*)(outf + token * 512 + lane * 8)     = o0;
        *(float4*)(outf + token * 512 + lane * 8 + 4) = o1;
    }
}

// ---------------------------------------------------------------------------
// GEMM: C[M,N] = A[M,K] * Bt[N,K]^T  (both bf16, row-major over K)
// 128x128 tile, 4 waves (2x2), each wave 64x64 via 4x4 frags of 16x16x32.
// MODE 0: Cb = bf16(acc + bias[c])                       (QKV)
// MODE 1: Cf = acc + bias[c] + X                         (proj + residual)
// MODE 2: Cb = bf16(gelu(acc))                           (FFN up)
// MODE 3: Cf = X + 0.5*acc                               (FFN down, branch 0)
// MODE 4: Cf += 0.5*acc                                  (FFN down, branch 1)
// ---------------------------------------------------------------------------
template<int MODE>
__global__ __launch_bounds__(256) void gemm_kernel(
    const ushort_t* __restrict__ A, const ushort_t* __restrict__ Bt,
    float* Cf, ushort_t* __restrict__ Cb,
    const float* __restrict__ bias, const float* __restrict__ X,
    int M, int N, int K)
{
    __shared__ __align__(16) ushort_t As[128 * 40];
    __shared__ __align__(16) ushort_t Bs[128 * 40];
    const int tid  = threadIdx.x;
    const int lane = tid & 63;
    const int wave = tid >> 6;
    const int bm = blockIdx.y * 128;
    const int bn = blockIdx.x * 128;
    const int wr = (wave >> 1) * 64;
    const int wc = (wave & 1) * 64;

    f32x4 acc[4][4] = {};

    for (int k0 = 0; k0 < K; k0 += 32) {
        __syncthreads();
        #pragma unroll
        for (int r = 0; r < 2; r++) {
            int li = r * 256 + tid;
            int row = li >> 2;
            int c8 = (li & 3) * 8;
            uint4 va = *(const uint4*)(A + (size_t)(bm + row) * K + k0 + c8);
            *(uint4*)(&As[row * 40 + c8]) = va;
            uint4 vb = *(const uint4*)(Bt + (size_t)(bn + row) * K + k0 + c8);
            *(uint4*)(&Bs[row * 40 + c8]) = vb;
        }
        __syncthreads();
        bf16x8 af[4], bf[4];
        #pragma unroll
        for (int mi = 0; mi < 4; mi++)
            af[mi] = *(const bf16x8*)(&As[(wr + mi * 16 + (lane & 15)) * 40 + (lane >> 4) * 8]);
        #pragma unroll
        for (int ni = 0; ni < 4; ni++)
            bf[ni] = *(const bf16x8*)(&Bs[(wc + ni * 16 + (lane & 15)) * 40 + (lane >> 4) * 8]);
        #pragma unroll
        for (int mi = 0; mi < 4; mi++)
            #pragma unroll
            for (int ni = 0; ni < 4; ni++)
                acc[mi][ni] = __builtin_amdgcn_mfma_f32_16x16x32_bf16(af[mi], bf[ni], acc[mi][ni], 0, 0, 0);
    }

    #pragma unroll
    for (int mi = 0; mi < 4; mi++) {
        #pragma unroll
        for (int ni = 0; ni < 4; ni++) {
            #pragma unroll
            for (int j = 0; j < 4; j++) {
                int r = bm + wr + mi * 16 + (lane >> 4) * 4 + j;
                int c = bn + wc + ni * 16 + (lane & 15);
                float v = acc[mi][ni][j];
                size_t idx = (size_t)r * N + c;
                if (MODE == 0)      { Cb[idx] = f2bf(v + bias[c]); }
                else if (MODE == 1) { Cf[idx] = v + bias[c] + X[idx]; }
                else if (MODE == 2) { Cb[idx] = f2bf(gelu_exact(v)); }
                else if (MODE == 3) { Cf[idx] = X[idx] + 0.5f * v; }
                else                { Cf[idx] = Cf[idx] + 0.5f * v; }
            }
        }
    }
}

// ---------------------------------------------------------------------------
// Fused causal attention, flash-style (online softmax).
// Block = 4 waves; each wave owns 16 query rows; block covers 64 rows of one
// (b,h). K/V chunked 32 keys at a time through LDS. QKV layout: [token][1536]
// with q at h*128, k at 512+h*128, v at 1024+h*128. Token indices are
// chunk-local (QKV points at this chunk's buffer).
// ---------------------------------------------------------------------------
__global__ __launch_bounds__(256) void attn_kernel(const ushort_t* __restrict__ QKV,
                                                   ushort_t* __restrict__ Ao) {
    __shared__ __align__(16) ushort_t Ks[32 * 136];
    __shared__ __align__(16) ushort_t VsT[128 * 40];
    __shared__ __align__(16) ushort_t Ps[4][16 * 40];
    const int tid  = threadIdx.x;
    const int lane = tid & 63;
    const int wave = tid >> 6;
    const int qtile = blockIdx.x;                 // 0..3
    const int bh = blockIdx.y;                    // local_b * 4 + h
    const int b = bh >> 2;
    const int h = bh & 3;
    const int qb = qtile * 64;
    const int q0 = qb + wave * 16;
    const size_t baseTok = (size_t)b * T_SEQ;

    bf16x8 qf[4];
    {
        const ushort_t* qrow = QKV + (baseTok + q0 + (lane & 15)) * 1536 + h * 128 + (lane >> 4) * 8;
        #pragma unroll
        for (int dc = 0; dc < 4; dc++)
            qf[dc] = *(const bf16x8*)(qrow + dc * 32);
    }

    float m_run[4], l_run[4];
    f32x4 o[8];
    #pragma unroll
    for (int j = 0; j < 4; j++) { m_run[j] = -INFINITY; l_run[j] = 0.0f; }
    #pragma unroll
    for (int nt = 0; nt < 8; nt++) o[nt] = f32x4{0.f, 0.f, 0.f, 0.f};

    const int nchunks = qtile * 2 + 2;
    for (int kc = 0; kc < nchunks; kc++) {
        const int kbase = kc * 32;
        __syncthreads();
        #pragma unroll
        for (int r = 0; r < 2; r++) {
            int li = r * 256 + tid;
            int row = li >> 4;               // 0..31 key within chunk
            int c8 = (li & 15) * 8;          // 0..120 d
            size_t g = (baseTok + kbase + row) * 1536;
            uint4 vk = *(const uint4*)(QKV + g + 512 + h * 128 + c8);
            *(uint4*)(&Ks[row * 136 + c8]) = vk;
            uint4 vv = *(const uint4*)(QKV + g + 1024 + h * 128 + c8);
            ushort_t* pv = (ushort_t*)&vv;
            #pragma unroll
            for (int jj = 0; jj < 8; jj++)
                VsT[(c8 + jj) * 40 + row] = pv[jj];
        }
        __syncthreads();

        if (q0 + 15 >= kbase) {
            f32x4 s0 = {0.f,0.f,0.f,0.f}, s1 = {0.f,0.f,0.f,0.f};
            #pragma unroll
            for (int dc = 0; dc < 4; dc++) {
                bf16x8 kf0 = *(const bf16x8*)(&Ks[(lane & 15) * 136 + dc * 32 + (lane >> 4) * 8]);
                bf16x8 kf1 = *(const bf16x8*)(&Ks[(16 + (lane & 15)) * 136 + dc * 32 + (lane >> 4) * 8]);
                s0 = __builtin_amdgcn_mfma_f32_16x16x32_bf16(qf[dc], kf0, s0, 0, 0, 0);
                s1 = __builtin_amdgcn_mfma_f32_16x16x32_bf16(qf[dc], kf1, s1, 0, 0, 0);
            }
            const int key0 = kbase + (lane & 15);
            const int key1 = key0 + 16;
            float p0[4], p1[4], alpha[4];
            #pragma unroll
            for (int j = 0; j < 4; j++) {
                int qrow = q0 + (lane >> 4) * 4 + j;
                float sv0 = (key0 <= qrow) ? s0[j] * SM_SCALE : -INFINITY;
                float sv1 = (key1 <= qrow) ? s1[j] * SM_SCALE : -INFINITY;
                float mx = fmaxf(sv0, sv1);
                #pragma unroll
                for (int d = 1; d < 16; d <<= 1) mx = fmaxf(mx, __shfl_xor(mx, d));
                float mnew = fmaxf(m_run[j], mx);
                float a = expf(m_run[j] - mnew);     // first chunk: exp(-inf)=0
                p0[j] = expf(sv0 - mnew);
                p1[j] = expf(sv1 - mnew);
                float rs = p0[j] + p1[j];
                #pragma unroll
                for (int d = 1; d < 16; d <<= 1) rs += __shfl_xor(rs, d);
                l_run[j] = l_run[j] * a + rs;
                m_run[j] = mnew;
                alpha[j] = a;
            }
            #pragma unroll
            for (int nt = 0; nt < 8; nt++)
                #pragma unroll
                for (int j = 0; j < 4; j++) o[nt][j] *= alpha[j];
            #pragma unroll
            for (int j = 0; j < 4; j++) {
                int rloc = (lane >> 4) * 4 + j;
                Ps[wave][rloc * 40 + (lane & 15)]      = f2bf(p0[j]);
                Ps[wave][rloc * 40 + 16 + (lane & 15)] = f2bf(p1[j]);
            }
            bf16x8 pa = *(const bf16x8*)(&Ps[wave][(lane & 15) * 40 + (lane >> 4) * 8]);
            #pragma unroll
            for (int nt = 0; nt < 8; nt++) {
                bf16x8 vf = *(const bf16x8*)(&VsT[(nt * 16 + (lane & 15)) * 40 + (lane >> 4) * 8]);
                o[nt] = __builtin_amdgcn_mfma_f32_16x16x32_bf16(pa, vf, o[nt], 0, 0, 0);
            }
        }
    }

    #pragma unroll
    for (int j = 0; j < 4; j++) {
        float inv = 1.0f / l_run[j];
        size_t row = baseTok + q0 + (lane >> 4) * 4 + j;
        #pragma unroll
        for (int nt = 0; nt < 8; nt++)
            Ao[row * 512 + h * 128 + nt * 16 + (lane & 15)] = f2bf(o[nt][j] * inv);
    }
}

// ---------------------------------------------------------------------------
extern "C" void kernel_launch(void* const* d_in, const int* in_sizes, int n_in,
                              void* d_out, int out_size, void* d_ws, size_t ws_size,
                              hipStream_t stream) {
    const float* x     = (const float*)d_in[0];
    const float* Wq    = (const float*)d_in[1];
    const float* Wk    = (const float*)d_in[2];
    const float* bk    = (const float*)d_in[3];
    const float* Wv    = (const float*)d_in[4];
    const float* Wproj = (const float*)d_in[5];
    const float* bproj = (const float*)d_in[6];
    const float* w1    = (const float*)d_in[7];
    const float* w2    = (const float*)d_in[8];
    const float* Wi    = (const float*)d_in[9];
    const float* Wo    = (const float*)d_in[10];
    float* out = (float*)d_out;   // also serves as the f32 residual/z/x2 buffer
    (void)in_sizes; (void)n_in; (void)out_size;

    char* ws = (char*)d_ws;
    size_t off = 0;
    auto alloc = [&](size_t bytes) -> void* {
        void* p = ws + off;
        off += (bytes + 255) & ~(size_t)255;
        return p;
    };
    // ---- persistent weights (prepped once per call) ----
    ushort_t* WqkvT    = (ushort_t*)alloc((size_t)1536 * 512 * 2);
    float*    bias1536 = (float*)   alloc((size_t)1536 * 4);
    ushort_t* WprojT   = (ushort_t*)alloc((size_t)512 * 512 * 2);
    ushort_t* WiT      = (ushort_t*)alloc((size_t)2 * 2048 * 512 * 2);
    ushort_t* WoT      = (ushort_t*)alloc((size_t)2 * 2048 * 512 * 2);
    const size_t weightBytes = off;

    // ---- choose batch-chunk count so scratch fits ws_size ----
    // per-chunk scratch: hb = Mc*512*2 bytes, big = Mc*2048*2 bytes
    int nchunks = 1;
    while (nchunks < 64) {
        size_t Mc = (size_t)TOKENS / nchunks;
        size_t need = weightBytes + Mc * 512 * 2 + Mc * 2048 * 2 + 4096;
        if (need <= ws_size) break;
        nchunks *= 2;
    }
    const size_t Mc = (size_t)TOKENS / nchunks;          // tokens per chunk (multiple of 2048)
    const int    nbChunk = B_BATCH / nchunks;            // batches per chunk

    ushort_t* hb  = (ushort_t*)alloc(Mc * 512 * 2);      // h -> attn out -> x2 bf16 (time-shared)
    ushort_t* big = (ushort_t*)alloc(Mc * 2048 * 2);     // qkv (1536 wide) -> hmid (2048 wide)

    // ---- weight prep ----
    prep_qkv <<<(1536 * 512 + 255) / 256, 256, 0, stream>>>(Wq, Wk, Wv, WqkvT);
    prep_bias<<<6, 256, 0, stream>>>(bk, bias1536);
    prep_proj<<<1024, 256, 0, stream>>>(Wproj, WprojT);
    prep_wi  <<<8192, 256, 0, stream>>>(Wi, WiT);
    prep_wo  <<<8192, 256, 0, stream>>>(Wo, WoT);

    for (int ck = 0; ck < nchunks; ck++) {
        const size_t t0 = (size_t)ck * Mc;
        const float* xC   = x + t0 * 512;
        float*       zC   = out + t0 * 512;
        const int    Mi   = (int)Mc;

        // h = rmsnorm(x, w1) -> hb (bf16)
        rmsnorm_kernel<0><<<Mi / 4, 256, 0, stream>>>(xC, w1, hb, nullptr);
        // QKV = h @ WqkvT^T + bias -> big (bf16, width 1536)
        gemm_kernel<0><<<dim3(1536 / 128, Mi / 128), 256, 0, stream>>>(
            hb, WqkvT, nullptr, big, bias1536, nullptr, Mi, 1536, 512);
        // attention -> hb (bf16, width 512)
        attn_kernel<<<dim3(T_SEQ / 64, nbChunk * H_HEADS), 256, 0, stream>>>(big, hb);
        // z = x + attn @ Wproj + bproj -> zC (f32, lives in d_out)
        gemm_kernel<1><<<dim3(512 / 128, Mi / 128), 256, 0, stream>>>(
            hb, WprojT, zC, nullptr, bproj, xC, Mi, 512, 512);
        // x2 = rmsnorm(z, w2): bf16 -> hb, f32 in-place -> zC
        rmsnorm_kernel<1><<<Mi / 4, 256, 0, stream>>>(zC, w2, hb, zC);
        // dual FFN branches: out = x2 + 0.5*(ffn0 + ffn1)
        for (int br = 0; br < 2; br++) {
            gemm_kernel<2><<<dim3(2048 / 128, Mi / 128), 256, 0, stream>>>(
                hb, WiT + (size_t)br * 2048 * 512, nullptr, big, nullptr, nullptr, Mi, 2048, 512);
            if (br == 0)
                gemm_kernel<3><<<dim3(512 / 128, Mi / 128), 256, 0, stream>>>(
                    big, WoT + (size_t)br * 512 * 2048, zC, nullptr, nullptr, zC, Mi, 512, 2048);
            else
                gemm_kernel<4><<<dim3(512 / 128, Mi / 128), 256, 0, stream>>>(
                    big, WoT + (size_t)br * 512 * 2048, zC, nullptr, nullptr, nullptr, Mi, 512, 2048);
        }
    }
}

// Round 3
// 3520.728 us; speedup vs baseline: 1.0364x; 1.0364x over previous
//
#include <hip/hip_runtime.h>
#include <cstdint>
#include <cstddef>

#define TOKENS 131072      // B*T = 512*256
#define B_BATCH 512
#define T_SEQ 256
#define C_DIM 512
#define H_HEADS 4
#define HS_DIM 128
#define FF_DIM 2048
#define EPS_RMS 1e-8f
#define SM_SCALE 0.044194173824159216f   // 512^-0.5

typedef short bf16x8 __attribute__((ext_vector_type(8)));
typedef float f32x4 __attribute__((ext_vector_type(4)));
typedef unsigned short ushort_t;

__device__ __forceinline__ ushort_t f2bf(float f) {
    uint32_t u = __builtin_bit_cast(uint32_t, f);
    u += 0x7FFFu + ((u >> 16) & 1u);   // round-to-nearest-even
    return (ushort_t)(u >> 16);
}

__device__ __forceinline__ float gelu_exact(float v) {
    return 0.5f * v * (1.0f + erff(v * 0.70710678118654752f));
}

// async global->LDS, 16 bytes per lane (global_load_lds_dwordx4).
// LDS dest must be wave-uniform base (HW writes base + lane*16); global src is per-lane.
__device__ __forceinline__ void async_copy16(ushort_t* lds, const ushort_t* g) {
    __builtin_amdgcn_global_load_lds(
        (const __attribute__((address_space(1))) uint32_t*)g,
        (__attribute__((address_space(3))) uint32_t*)lds,
        16, 0, 0);
}

// ---------------------------------------------------------------------------
// Weight prep: fp32 -> bf16, transposed to N x K row-major
// ---------------------------------------------------------------------------
__global__ void prep_qkv(const float* __restrict__ Wq, const float* __restrict__ Wk,
                         const float* __restrict__ Wv, ushort_t* __restrict__ WqkvT) {
    int idx = blockIdx.x * 256 + threadIdx.x;       // over 1536*512
    if (idx >= 1536 * 512) return;
    int n = idx >> 9;
    int k = idx & 511;
    int h = (n & 511) >> 7;
    int d = n & 127;
    float v;
    size_t s = ((size_t)h * 512 + k) * 128 + d;     // (H,C,HS)
    if (n < 512)       v = Wq[s];
    else if (n < 1024) v = Wk[s];
    else               v = Wv[s];
    WqkvT[idx] = f2bf(v);
}

__global__ void prep_bias(const float* __restrict__ bk, float* __restrict__ bias1536) {
    int n = blockIdx.x * 256 + threadIdx.x;
    if (n >= 1536) return;
    bias1536[n] = (n >= 512 && n < 1024) ? bk[n - 512] : 0.0f;   // bk flat (H,HS)
}

__global__ void prep_proj(const float* __restrict__ Wproj, ushort_t* __restrict__ WprojT) {
    int idx = blockIdx.x * 256 + threadIdx.x;       // over 512*512
    if (idx >= 512 * 512) return;
    int n = idx >> 9, k = idx & 511;
    WprojT[idx] = f2bf(Wproj[(size_t)k * 512 + n]);
}

__global__ void prep_wi(const float* __restrict__ Wi, ushort_t* __restrict__ WiT) {
    int idx = blockIdx.x * 256 + threadIdx.x;       // over 2*2048*512
    if (idx >= 2 * 2048 * 512) return;
    int b = idx >> 20;
    int rem = idx & 1048575;
    int f = rem >> 9, c = rem & 511;                // WiT[b][f][c]
    WiT[idx] = f2bf(Wi[((size_t)b * 512 + c) * 2048 + f]);
}

__global__ void prep_wo(const float* __restrict__ Wo, ushort_t* __restrict__ WoT) {
    int idx = blockIdx.x * 256 + threadIdx.x;       // over 2*512*2048
    if (idx >= 2 * 512 * 2048) return;
    int b = idx >> 20;
    int rem = idx & 1048575;
    int c = rem >> 11, f = rem & 2047;              // WoT[b][c][f]
    WoT[idx] = f2bf(Wo[((size_t)b * 2048 + f) * 512 + c]);
}

// ---------------------------------------------------------------------------
// RMSNorm: one wave per token (512 floats, 8/lane)
// ---------------------------------------------------------------------------
template<int WRITE_F32>
__global__ __launch_bounds__(256) void rmsnorm_kernel(const float* __restrict__ in,
                                                      const float* __restrict__ wptr,
                                                      ushort_t* __restrict__ outb,
                                                      float* outf) {
    const int lane = threadIdx.x & 63;
    const int wave = threadIdx.x >> 6;
    const size_t token = (size_t)blockIdx.x * 4 + wave;
    const float* row = in + token * 512;
    float4 v0 = *(const float4*)(row + lane * 8);
    float4 v1 = *(const float4*)(row + lane * 8 + 4);
    float ss = v0.x*v0.x + v0.y*v0.y + v0.z*v0.z + v0.w*v0.w
             + v1.x*v1.x + v1.y*v1.y + v1.z*v1.z + v1.w*v1.w;
    #pragma unroll
    for (int d = 32; d; d >>= 1) ss += __shfl_xor(ss, d);
    float scale = wptr[0] * rsqrtf(ss * (1.0f / 512.0f) + EPS_RMS);
    float vals[8] = {v0.x, v0.y, v0.z, v0.w, v1.x, v1.y, v1.z, v1.w};
    union { ushort_t us[8]; uint4 u4; } pk;
    #pragma unroll
    for (int i = 0; i < 8; i++) pk.us[i] = f2bf(vals[i] * scale);
    *(uint4*)(outb + token * 512 + lane * 8) = pk.u4;
    if (WRITE_F32) {
        float4 o0 = make_float4(v0.x*scale, v0.y*scale, v0.z*scale, v0.w*scale);
        float4 o1 = make_float4(v1.x*scale, v1.y*scale, v1.z*scale, v1.w*scale);
        *(float4*)(outf + token * 512 + lane * 8)     = o0;
        *(float4*)(outf + token * 512 + lane * 8 + 4) = o1;
    }
}

// ---------------------------------------------------------------------------
// GEMM (m97 structure): C[M,N] = A[M,K] * Bt[N,K]^T  (bf16, row-major over K)
// 128x128 tile, BK=32, 4 waves (2x2), 4x4 frags of 16x16x32 each.
// Staging: global_load_lds width=16, linear LDS [128][32] per operand.
// Grid is flattened 1-D with XCD-chunked swizzle (nwg % 8 == 0 guaranteed).
// MODE 0: Cb = bf16(acc + bias[c])                       (QKV)
// MODE 1: Cf = acc + bias[c] + X                         (proj + residual)
// MODE 2: Cb = bf16(gelu(acc))                           (FFN up)
// MODE 3: Cf = X + 0.5*acc                               (FFN down, branch 0)
// MODE 4: Cf += 0.5*acc                                  (FFN down, branch 1)
// ---------------------------------------------------------------------------
template<int MODE>
__global__ __launch_bounds__(256) void gemm_kernel(
    const ushort_t* __restrict__ A, const ushort_t* __restrict__ Bt,
    float* Cf, ushort_t* __restrict__ Cb,
    const float* __restrict__ bias, const float* __restrict__ X,
    int N, int K)
{
    __shared__ __align__(16) ushort_t As[128 * 32];
    __shared__ __align__(16) ushort_t Bs[128 * 32];
    const int tid  = threadIdx.x;
    const int lane = tid & 63;
    const int wave = tid >> 6;

    // XCD-chunked bijective swizzle: orig%8 = XCD (round-robin dispatch);
    // give each XCD a contiguous wgid range so same-bm blocks share an XCD L2.
    const int nwg  = (int)gridDim.x;
    const int orig = (int)blockIdx.x;
    const int wgid = (orig & 7) * (nwg >> 3) + (orig >> 3);
    const int gx   = N >> 7;
    const int bm = (wgid / gx) << 7;
    const int bn = (wgid % gx) << 7;

    const int wr = (wave >> 1) * 64;
    const int wc = (wave & 1) * 64;

    // staging addresses: wave w stages rows [w*32, w*32+32) of each tile,
    // two wave-instructions of 16 rows (16 rows x 64 B = 1024 B = 64 lanes x 16 B)
    const int srow = wave * 32 + (lane >> 2);
    const int scol = (lane & 3) * 8;
    const ushort_t* gA = A  + (size_t)(bm + srow) * K + scol;
    const ushort_t* gB = Bt + (size_t)(bn + srow) * K + scol;
    ushort_t* lA = As + wave * 32 * 32;     // wave-uniform
    ushort_t* lB = Bs + wave * 32 * 32;

    // fragment read base: row = wr + mi*16 + (lane&15), k = (lane>>4)*8
    const ushort_t* rA = As + (wr + (lane & 15)) * 32 + (lane >> 4) * 8;
    const ushort_t* rB = Bs + (wc + (lane & 15)) * 32 + (lane >> 4) * 8;

    f32x4 acc[4][4] = {};

    for (int k0 = 0; k0 < K; k0 += 32) {
        async_copy16(lA,             gA + k0);
        async_copy16(lA + 16 * 32,   gA + (size_t)16 * K + k0);
        async_copy16(lB,             gB + k0);
        async_copy16(lB + 16 * 32,   gB + (size_t)16 * K + k0);
        __syncthreads();
        bf16x8 af[4], bf[4];
        #pragma unroll
        for (int mi = 0; mi < 4; mi++) af[mi] = *(const bf16x8*)(rA + mi * 16 * 32);
        #pragma unroll
        for (int ni = 0; ni < 4; ni++) bf[ni] = *(const bf16x8*)(rB + ni * 16 * 32);
        #pragma unroll
        for (int mi = 0; mi < 4; mi++)
            #pragma unroll
            for (int ni = 0; ni < 4; ni++)
                acc[mi][ni] = __builtin_amdgcn_mfma_f32_16x16x32_bf16(af[mi], bf[ni], acc[mi][ni], 0, 0, 0);
        __syncthreads();
    }

    #pragma unroll
    for (int mi = 0; mi < 4; mi++) {
        #pragma unroll
        for (int ni = 0; ni < 4; ni++) {
            #pragma unroll
            for (int j = 0; j < 4; j++) {
                int r = bm + wr + mi * 16 + (lane >> 4) * 4 + j;
                int c = bn + wc + ni * 16 + (lane & 15);
                float v = acc[mi][ni][j];
                size_t idx = (size_t)r * N + c;
                if (MODE == 0)      { Cb[idx] = f2bf(v + bias[c]); }
                else if (MODE == 1) { Cf[idx] = v + bias[c] + X[idx]; }
                else if (MODE == 2) { Cb[idx] = f2bf(gelu_exact(v)); }
                else if (MODE == 3) { Cf[idx] = X[idx] + 0.5f * v; }
                else                { Cf[idx] = Cf[idx] + 0.5f * v; }
            }
        }
    }
}

// ---------------------------------------------------------------------------
// Fused causal attention, flash-style (online softmax).
// Block = 4 waves; each wave owns 16 query rows; block covers 64 rows of one
// (b,h). K/V chunked 32 keys at a time through LDS. QKV layout: [token][1536]
// with q at h*128, k at 512+h*128, v at 1024+h*128. Token indices are
// chunk-local (QKV points at this chunk's buffer).
// ---------------------------------------------------------------------------
__global__ __launch_bounds__(256) void attn_kernel(const ushort_t* __restrict__ QKV,
                                                   ushort_t* __restrict__ Ao) {
    __shared__ __align__(16) ushort_t Ks[32 * 136];
    __shared__ __align__(16) ushort_t VsT[128 * 40];
    __shared__ __align__(16) ushort_t Ps[4][16 * 40];
    const int tid  = threadIdx.x;
    const int lane = tid & 63;
    const int wave = tid >> 6;
    const int qtile = blockIdx.x;                 // 0..3
    const int bh = blockIdx.y;                    // local_b * 4 + h
    const int b = bh >> 2;
    const int h = bh & 3;
    const int qb = qtile * 64;
    const int q0 = qb + wave * 16;
    const size_t baseTok = (size_t)b * T_SEQ;

    bf16x8 qf[4];
    {
        const ushort_t* qrow = QKV + (baseTok + q0 + (lane & 15)) * 1536 + h * 128 + (lane >> 4) * 8;
        #pragma unroll
        for (int dc = 0; dc < 4; dc++)
            qf[dc] = *(const bf16x8*)(qrow + dc * 32);
    }

    float m_run[4], l_run[4];
    f32x4 o[8];
    #pragma unroll
    for (int j = 0; j < 4; j++) { m_run[j] = -INFINITY; l_run[j] = 0.0f; }
    #pragma unroll
    for (int nt = 0; nt < 8; nt++) o[nt] = f32x4{0.f, 0.f, 0.f, 0.f};

    const int nchunks = qtile * 2 + 2;
    for (int kc = 0; kc < nchunks; kc++) {
        const int kbase = kc * 32;
        __syncthreads();
        #pragma unroll
        for (int r = 0; r < 2; r++) {
            int li = r * 256 + tid;
            int row = li >> 4;               // 0..31 key within chunk
            int c8 = (li & 15) * 8;          // 0..120 d
            size_t g = (baseTok + kbase + row) * 1536;
            uint4 vk = *(const uint4*)(QKV + g + 512 + h * 128 + c8);
            *(uint4*)(&Ks[row * 136 + c8]) = vk;
            uint4 vv = *(const uint4*)(QKV + g + 1024 + h * 128 + c8);
            ushort_t* pv = (ushort_t*)&vv;
            #pragma unroll
            for (int jj = 0; jj < 8; jj++)
                VsT[(c8 + jj) * 40 + row] = pv[jj];
        }
        __syncthreads();

        if (q0 + 15 >= kbase) {
            f32x4 s0 = {0.f,0.f,0.f,0.f}, s1 = {0.f,0.f,0.f,0.f};
            #pragma unroll
            for (int dc = 0; dc < 4; dc++) {
                bf16x8 kf0 = *(const bf16x8*)(&Ks[(lane & 15) * 136 + dc * 32 + (lane >> 4) * 8]);
                bf16x8 kf1 = *(const bf16x8*)(&Ks[(16 + (lane & 15)) * 136 + dc * 32 + (lane >> 4) * 8]);
                s0 = __builtin_amdgcn_mfma_f32_16x16x32_bf16(qf[dc], kf0, s0, 0, 0, 0);
                s1 = __builtin_amdgcn_mfma_f32_16x16x32_bf16(qf[dc], kf1, s1, 0, 0, 0);
            }
            const int key0 = kbase + (lane & 15);
            const int key1 = key0 + 16;
            float p0[4], p1[4], alpha[4];
            #pragma unroll
            for (int j = 0; j < 4; j++) {
                int qrow = q0 + (lane >> 4) * 4 + j;
                float sv0 = (key0 <= qrow) ? s0[j] * SM_SCALE : -INFINITY;
                float sv1 = (key1 <= qrow) ? s1[j] * SM_SCALE : -INFINITY;
                float mx = fmaxf(sv0, sv1);
                #pragma unroll
                for (int d = 1; d < 16; d <<= 1) mx = fmaxf(mx, __shfl_xor(mx, d));
                float mnew = fmaxf(m_run[j], mx);
                float a = expf(m_run[j] - mnew);     // first chunk: exp(-inf)=0
                p0[j] = expf(sv0 - mnew);
                p1[j] = expf(sv1 - mnew);
                float rs = p0[j] + p1[j];
                #pragma unroll
                for (int d = 1; d < 16; d <<= 1) rs += __shfl_xor(rs, d);
                l_run[j] = l_run[j] * a + rs;
                m_run[j] = mnew;
                alpha[j] = a;
            }
            #pragma unroll
            for (int nt = 0; nt < 8; nt++)
                #pragma unroll
                for (int j = 0; j < 4; j++) o[nt][j] *= alpha[j];
            #pragma unroll
            for (int j = 0; j < 4; j++) {
                int rloc = (lane >> 4) * 4 + j;
                Ps[wave][rloc * 40 + (lane & 15)]      = f2bf(p0[j]);
                Ps[wave][rloc * 40 + 16 + (lane & 15)] = f2bf(p1[j]);
            }
            bf16x8 pa = *(const bf16x8*)(&Ps[wave][(lane & 15) * 40 + (lane >> 4) * 8]);
            #pragma unroll
            for (int nt = 0; nt < 8; nt++) {
                bf16x8 vf = *(const bf16x8*)(&VsT[(nt * 16 + (lane & 15)) * 40 + (lane >> 4) * 8]);
                o[nt] = __builtin_amdgcn_mfma_f32_16x16x32_bf16(pa, vf, o[nt], 0, 0, 0);
            }
        }
    }

    #pragma unroll
    for (int j = 0; j < 4; j++) {
        float inv = 1.0f / l_run[j];
        size_t row = baseTok + q0 + (lane >> 4) * 4 + j;
        #pragma unroll
        for (int nt = 0; nt < 8; nt++)
            Ao[row * 512 + h * 128 + nt * 16 + (lane & 15)] = f2bf(o[nt][j] * inv);
    }
}

// ---------------------------------------------------------------------------
extern "C" void kernel_launch(void* const* d_in, const int* in_sizes, int n_in,
                              void* d_out, int out_size, void* d_ws, size_t ws_size,
                              hipStream_t stream) {
    const float* x     = (const float*)d_in[0];
    const float* Wq    = (const float*)d_in[1];
    const float* Wk    = (const float*)d_in[2];
    const float* bk    = (const float*)d_in[3];
    const float* Wv    = (const float*)d_in[4];
    const float* Wproj = (const float*)d_in[5];
    const float* bproj = (const float*)d_in[6];
    const float* w1    = (const float*)d_in[7];
    const float* w2    = (const float*)d_in[8];
    const float* Wi    = (const float*)d_in[9];
    const float* Wo    = (const float*)d_in[10];
    float* out = (float*)d_out;   // also serves as the f32 residual/z/x2 buffer
    (void)in_sizes; (void)n_in; (void)out_size;

    char* ws = (char*)d_ws;
    size_t off = 0;
    auto alloc = [&](size_t bytes) -> void* {
        void* p = ws + off;
        off += (bytes + 255) & ~(size_t)255;
        return p;
    };
    // ---- persistent weights (prepped once per call) ----
    ushort_t* WqkvT    = (ushort_t*)alloc((size_t)1536 * 512 * 2);
    float*    bias1536 = (float*)   alloc((size_t)1536 * 4);
    ushort_t* WprojT   = (ushort_t*)alloc((size_t)512 * 512 * 2);
    ushort_t* WiT      = (ushort_t*)alloc((size_t)2 * 2048 * 512 * 2);
    ushort_t* WoT      = (ushort_t*)alloc((size_t)2 * 2048 * 512 * 2);
    const size_t weightBytes = off;

    // ---- choose batch-chunk count so scratch fits ws_size ----
    int nchunks = 1;
    while (nchunks < 64) {
        size_t Mc = (size_t)TOKENS / nchunks;
        size_t need = weightBytes + Mc * 512 * 2 + Mc * 2048 * 2 + 4096;
        if (need <= ws_size) break;
        nchunks *= 2;
    }
    const size_t Mc = (size_t)TOKENS / nchunks;          // tokens per chunk
    const int    nbChunk = B_BATCH / nchunks;            // batches per chunk

    ushort_t* hb  = (ushort_t*)alloc(Mc * 512 * 2);      // h -> attn out -> x2 bf16 (time-shared)
    ushort_t* big = (ushort_t*)alloc(Mc * 2048 * 2);     // qkv (1536 wide) -> hmid (2048 wide)

    // ---- weight prep ----
    prep_qkv <<<(1536 * 512 + 255) / 256, 256, 0, stream>>>(Wq, Wk, Wv, WqkvT);
    prep_bias<<<6, 256, 0, stream>>>(bk, bias1536);
    prep_proj<<<1024, 256, 0, stream>>>(Wproj, WprojT);
    prep_wi  <<<8192, 256, 0, stream>>>(Wi, WiT);
    prep_wo  <<<8192, 256, 0, stream>>>(Wo, WoT);

    for (int ck = 0; ck < nchunks; ck++) {
        const size_t t0 = (size_t)ck * Mc;
        const float* xC   = x + t0 * 512;
        float*       zC   = out + t0 * 512;
        const int    Mi   = (int)Mc;
        const int    mt   = Mi / 128;                    // M-tiles

        // h = rmsnorm(x, w1) -> hb (bf16)
        rmsnorm_kernel<0><<<Mi / 4, 256, 0, stream>>>(xC, w1, hb, nullptr);
        // QKV = h @ WqkvT^T + bias -> big (bf16, width 1536)
        gemm_kernel<0><<<mt * 12, 256, 0, stream>>>(
            hb, WqkvT, nullptr, big, bias1536, nullptr, 1536, 512);
        // attention -> hb (bf16, width 512)
        attn_kernel<<<dim3(T_SEQ / 64, nbChunk * H_HEADS), 256, 0, stream>>>(big, hb);
        // z = x + attn @ Wproj + bproj -> zC (f32, lives in d_out)
        gemm_kernel<1><<<mt * 4, 256, 0, stream>>>(
            hb, WprojT, zC, nullptr, bproj, xC, 512, 512);
        // x2 = rmsnorm(z, w2): bf16 -> hb, f32 in-place -> zC
        rmsnorm_kernel<1><<<Mi / 4, 256, 0, stream>>>(zC, w2, hb, zC);
        // dual FFN branches: out = x2 + 0.5*(ffn0 + ffn1)
        for (int br = 0; br < 2; br++) {
            gemm_kernel<2><<<mt * 16, 256, 0, stream>>>(
                hb, WiT + (size_t)br * 2048 * 512, nullptr, big, nullptr, nullptr, 2048, 512);
            if (br == 0)
                gemm_kernel<3><<<mt * 4, 256, 0, stream>>>(
                    big, WoT + (size_t)br * 512 * 2048, zC, nullptr, nullptr, zC, 512, 2048);
            else
                gemm_kernel<4><<<mt * 4, 256, 0, stream>>>(
                    big, WoT + (size_t)br * 512 * 2048, zC, nullptr, nullptr, nullptr, 512, 2048);
        }
    }
}

// Round 4
// 3142.772 us; speedup vs baseline: 1.1611x; 1.1203x over previous
//
#include <hip/hip_runtime.h>
#include <cstdint>
#include <cstddef>

#define TOKENS 131072      // B*T = 512*256
#define B_BATCH 512
#define T_SEQ 256
#define C_DIM 512
#define H_HEADS 4
#define HS_DIM 128
#define FF_DIM 2048
#define EPS_RMS 1e-8f
#define SM_SCALE 0.044194173824159216f   // 512^-0.5

typedef short bf16x8 __attribute__((ext_vector_type(8)));
typedef float f32x4 __attribute__((ext_vector_type(4)));
typedef unsigned short ushort_t;

__device__ __forceinline__ ushort_t f2bf(float f) {
    uint32_t u = __builtin_bit_cast(uint32_t, f);
    u += 0x7FFFu + ((u >> 16) & 1u);   // round-to-nearest-even
    return (ushort_t)(u >> 16);
}

__device__ __forceinline__ float gelu_exact(float v) {
    return 0.5f * v * (1.0f + erff(v * 0.70710678118654752f));
}

// async global->LDS, 16 bytes per lane (global_load_lds_dwordx4).
// LDS dest must be wave-uniform base (HW writes base + lane*16); global src is per-lane.
__device__ __forceinline__ void async_copy16(ushort_t* lds, const ushort_t* g) {
    __builtin_amdgcn_global_load_lds(
        (const __attribute__((address_space(1))) uint32_t*)g,
        (__attribute__((address_space(3))) uint32_t*)lds,
        16, 0, 0);
}

// ---------------------------------------------------------------------------
// Weight prep: fp32 -> bf16, transposed to N x K row-major
// ---------------------------------------------------------------------------
__global__ void prep_qkv(const float* __restrict__ Wq, const float* __restrict__ Wk,
                         const float* __restrict__ Wv, ushort_t* __restrict__ WqkvT) {
    int idx = blockIdx.x * 256 + threadIdx.x;       // over 1536*512
    if (idx >= 1536 * 512) return;
    int n = idx >> 9;
    int k = idx & 511;
    int h = (n & 511) >> 7;
    int d = n & 127;
    float v;
    size_t s = ((size_t)h * 512 + k) * 128 + d;     // (H,C,HS)
    if (n < 512)       v = Wq[s];
    else if (n < 1024) v = Wk[s];
    else               v = Wv[s];
    WqkvT[idx] = f2bf(v);
}

__global__ void prep_bias(const float* __restrict__ bk, float* __restrict__ bias1536) {
    int n = blockIdx.x * 256 + threadIdx.x;
    if (n >= 1536) return;
    bias1536[n] = (n >= 512 && n < 1024) ? bk[n - 512] : 0.0f;   // bk flat (H,HS)
}

__global__ void prep_proj(const float* __restrict__ Wproj, ushort_t* __restrict__ WprojT) {
    int idx = blockIdx.x * 256 + threadIdx.x;       // over 512*512
    if (idx >= 512 * 512) return;
    int n = idx >> 9, k = idx & 511;
    WprojT[idx] = f2bf(Wproj[(size_t)k * 512 + n]);
}

__global__ void prep_wi(const float* __restrict__ Wi, ushort_t* __restrict__ WiT) {
    int idx = blockIdx.x * 256 + threadIdx.x;       // over 2*2048*512
    if (idx >= 2 * 2048 * 512) return;
    int b = idx >> 20;
    int rem = idx & 1048575;
    int f = rem >> 9, c = rem & 511;                // WiT[b*2048+f][c] = [4096][512]
    WiT[idx] = f2bf(Wi[((size_t)b * 512 + c) * 2048 + f]);
}

// WoT2[c][br*2048+f] = 0.5 * Wo[br][f][c]  -> [512][4096] row-major over K=4096
__global__ void prep_wo(const float* __restrict__ Wo, ushort_t* __restrict__ WoT2) {
    int idx = blockIdx.x * 256 + threadIdx.x;       // over 512*4096
    if (idx >= 512 * 4096) return;
    int c  = idx >> 12;
    int n2 = idx & 4095;
    int br = n2 >> 11;
    int f  = n2 & 2047;
    WoT2[idx] = f2bf(0.5f * Wo[(((size_t)br * 2048 + f) * 512) + c]);
}

// ---------------------------------------------------------------------------
// RMSNorm: one wave per token (512 floats, 8/lane)
// ---------------------------------------------------------------------------
template<int WRITE_F32>
__global__ __launch_bounds__(256) void rmsnorm_kernel(const float* __restrict__ in,
                                                      const float* __restrict__ wptr,
                                                      ushort_t* __restrict__ outb,
                                                      float* outf) {
    const int lane = threadIdx.x & 63;
    const int wave = threadIdx.x >> 6;
    const size_t token = (size_t)blockIdx.x * 4 + wave;
    const float* row = in + token * 512;
    float4 v0 = *(const float4*)(row + lane * 8);
    float4 v1 = *(const float4*)(row + lane * 8 + 4);
    float ss = v0.x*v0.x + v0.y*v0.y + v0.z*v0.z + v0.w*v0.w
             + v1.x*v1.x + v1.y*v1.y + v1.z*v1.z + v1.w*v1.w;
    #pragma unroll
    for (int d = 32; d; d >>= 1) ss += __shfl_xor(ss, d);
    float scale = wptr[0] * rsqrtf(ss * (1.0f / 512.0f) + EPS_RMS);
    float vals[8] = {v0.x, v0.y, v0.z, v0.w, v1.x, v1.y, v1.z, v1.w};
    union { ushort_t us[8]; uint4 u4; } pk;
    #pragma unroll
    for (int i = 0; i < 8; i++) pk.us[i] = f2bf(vals[i] * scale);
    *(uint4*)(outb + token * 512 + lane * 8) = pk.u4;
    if (WRITE_F32) {
        float4 o0 = make_float4(v0.x*scale, v0.y*scale, v0.z*scale, v0.w*scale);
        float4 o1 = make_float4(v1.x*scale, v1.y*scale, v1.z*scale, v1.w*scale);
        *(float4*)(outf + token * 512 + lane * 8)     = o0;
        *(float4*)(outf + token * 512 + lane * 8 + 4) = o1;
    }
}

// ---------------------------------------------------------------------------
// GEMM, 2-phase double-buffered (T3-minimum): C[M,N] = A[M,K] * Bt[N,K]^T
// 128x128 tile, BK=32, 4 waves (2x2), 4x4 frags of 16x16x32 each.
// Staging: global_load_lds width=16, linear LDS [128][32] per operand, x2 buf.
// Per K-step: issue next tile's loads FIRST, then ds_read+MFMA current, then
// one vmcnt(0)+barrier (inside __syncthreads) -> load latency hides under compute.
// Grid flattened 1-D with XCD-chunked swizzle (nwg % 8 == 0 guaranteed).
// MODE 0: Cb = bf16(acc + bias[c])                       (QKV)
// MODE 1: Cf = acc + bias[c] + X                         (proj + residual)
// MODE 2: Cb = bf16(gelu(acc))                           (FFN up, dual-branch N=4096)
// MODE 3: Cf = X + acc                                   (FFN down, K=4096, 0.5 in weights)
// ---------------------------------------------------------------------------
template<int MODE>
__global__ __launch_bounds__(256) void gemm_kernel(
    const ushort_t* __restrict__ A, const ushort_t* __restrict__ Bt,
    float* Cf, ushort_t* __restrict__ Cb,
    const float* __restrict__ bias, const float* __restrict__ X,
    int N, int K)
{
    __shared__ __align__(16) ushort_t As[2][128 * 32];
    __shared__ __align__(16) ushort_t Bs[2][128 * 32];
    const int tid  = threadIdx.x;
    const int lane = tid & 63;
    const int wave = tid >> 6;

    // XCD-chunked bijective swizzle: orig%8 = XCD (round-robin dispatch);
    // give each XCD a contiguous wgid range so same-bm blocks share an XCD L2.
    const int nwg  = (int)gridDim.x;
    const int orig = (int)blockIdx.x;
    const int wgid = (orig & 7) * (nwg >> 3) + (orig >> 3);
    const int gx   = N >> 7;
    const int bm = (wgid / gx) << 7;
    const int bn = (wgid % gx) << 7;

    const int wr = (wave >> 1) * 64;
    const int wc = (wave & 1) * 64;

    // staging: wave w stages rows [w*32, w*32+32), 2 instrs of 16 rows each
    const int srow = wave * 32 + (lane >> 2);
    const int scol = (lane & 3) * 8;
    const ushort_t* gA = A  + (size_t)(bm + srow) * K + scol;
    const ushort_t* gB = Bt + (size_t)(bn + srow) * K + scol;
    const int ldsOff = wave * 32 * 32;          // wave-uniform

    // fragment read bases (buffer 0); buffer stride = 128*32 elements
    const ushort_t* rA = &As[0][(wr + (lane & 15)) * 32 + (lane >> 4) * 8];
    const ushort_t* rB = &Bs[0][(wc + (lane & 15)) * 32 + (lane >> 4) * 8];

    f32x4 acc[4][4] = {};
    const int nt = K >> 5;

    // prologue: stage tile 0 into buf 0
    async_copy16(&As[0][ldsOff],           gA);
    async_copy16(&As[0][ldsOff + 16 * 32], gA + (size_t)16 * K);
    async_copy16(&Bs[0][ldsOff],           gB);
    async_copy16(&Bs[0][ldsOff + 16 * 32], gB + (size_t)16 * K);
    __syncthreads();

    for (int t = 0; t < nt; ++t) {
        const int buf = t & 1;
        if (t + 1 < nt) {
            const int k1 = (t + 1) << 5;
            const int nb = buf ^ 1;
            async_copy16(&As[nb][ldsOff],           gA + k1);
            async_copy16(&As[nb][ldsOff + 16 * 32], gA + (size_t)16 * K + k1);
            async_copy16(&Bs[nb][ldsOff],           gB + k1);
            async_copy16(&Bs[nb][ldsOff + 16 * 32], gB + (size_t)16 * K + k1);
        }
        const int bo = buf * 128 * 32;
        bf16x8 af[4], bfr[4];
        #pragma unroll
        for (int mi = 0; mi < 4; mi++) af[mi]  = *(const bf16x8*)(rA + bo + mi * 16 * 32);
        #pragma unroll
        for (int ni = 0; ni < 4; ni++) bfr[ni] = *(const bf16x8*)(rB + bo + ni * 16 * 32);
        #pragma unroll
        for (int mi = 0; mi < 4; mi++)
            #pragma unroll
            for (int ni = 0; ni < 4; ni++)
                acc[mi][ni] = __builtin_amdgcn_mfma_f32_16x16x32_bf16(af[mi], bfr[ni], acc[mi][ni], 0, 0, 0);
        __syncthreads();   // drains vmcnt(0): next tile landed; cur tile safe to overwrite
    }

    #pragma unroll
    for (int mi = 0; mi < 4; mi++) {
        #pragma unroll
        for (int ni = 0; ni < 4; ni++) {
            #pragma unroll
            for (int j = 0; j < 4; j++) {
                int r = bm + wr + mi * 16 + (lane >> 4) * 4 + j;
                int c = bn + wc + ni * 16 + (lane & 15);
                float v = acc[mi][ni][j];
                size_t idx = (size_t)r * N + c;
                if (MODE == 0)      { Cb[idx] = f2bf(v + bias[c]); }
                else if (MODE == 1) { Cf[idx] = v + bias[c] + X[idx]; }
                else if (MODE == 2) { Cb[idx] = f2bf(gelu_exact(v)); }
                else                { Cf[idx] = X[idx] + v; }
            }
        }
    }
}

// ---------------------------------------------------------------------------
// Fused causal attention, flash-style (online softmax).
// Block = 4 waves; each wave owns 16 query rows; block covers 64 rows of one
// (b,h). K/V chunked 32 keys at a time through LDS. QKV layout: [token][1536]
// with q at h*128, k at 512+h*128, v at 1024+h*128. Token indices are
// chunk-local (QKV points at this chunk's buffer).
// ---------------------------------------------------------------------------
__global__ __launch_bounds__(256) void attn_kernel(const ushort_t* __restrict__ QKV,
                                                   ushort_t* __restrict__ Ao) {
    __shared__ __align__(16) ushort_t Ks[32 * 136];
    __shared__ __align__(16) ushort_t VsT[128 * 40];
    __shared__ __align__(16) ushort_t Ps[4][16 * 40];
    const int tid  = threadIdx.x;
    const int lane = tid & 63;
    const int wave = tid >> 6;
    const int qtile = blockIdx.x;                 // 0..3
    const int bh = blockIdx.y;                    // local_b * 4 + h
    const int b = bh >> 2;
    const int h = bh & 3;
    const int qb = qtile * 64;
    const int q0 = qb + wave * 16;
    const size_t baseTok = (size_t)b * T_SEQ;

    bf16x8 qf[4];
    {
        const ushort_t* qrow = QKV + (baseTok + q0 + (lane & 15)) * 1536 + h * 128 + (lane >> 4) * 8;
        #pragma unroll
        for (int dc = 0; dc < 4; dc++)
            qf[dc] = *(const bf16x8*)(qrow + dc * 32);
    }

    float m_run[4], l_run[4];
    f32x4 o[8];
    #pragma unroll
    for (int j = 0; j < 4; j++) { m_run[j] = -INFINITY; l_run[j] = 0.0f; }
    #pragma unroll
    for (int nt = 0; nt < 8; nt++) o[nt] = f32x4{0.f, 0.f, 0.f, 0.f};

    const int nchunks = qtile * 2 + 2;
    for (int kc = 0; kc < nchunks; kc++) {
        const int kbase = kc * 32;
        __syncthreads();
        #pragma unroll
        for (int r = 0; r < 2; r++) {
            int li = r * 256 + tid;
            int row = li >> 4;               // 0..31 key within chunk
            int c8 = (li & 15) * 8;          // 0..120 d
            size_t g = (baseTok + kbase + row) * 1536;
            uint4 vk = *(const uint4*)(QKV + g + 512 + h * 128 + c8);
            *(uint4*)(&Ks[row * 136 + c8]) = vk;
            uint4 vv = *(const uint4*)(QKV + g + 1024 + h * 128 + c8);
            ushort_t* pv = (ushort_t*)&vv;
            #pragma unroll
            for (int jj = 0; jj < 8; jj++)
                VsT[(c8 + jj) * 40 + row] = pv[jj];
        }
        __syncthreads();

        if (q0 + 15 >= kbase) {
            f32x4 s0 = {0.f,0.f,0.f,0.f}, s1 = {0.f,0.f,0.f,0.f};
            #pragma unroll
            for (int dc = 0; dc < 4; dc++) {
                bf16x8 kf0 = *(const bf16x8*)(&Ks[(lane & 15) * 136 + dc * 32 + (lane >> 4) * 8]);
                bf16x8 kf1 = *(const bf16x8*)(&Ks[(16 + (lane & 15)) * 136 + dc * 32 + (lane >> 4) * 8]);
                s0 = __builtin_amdgcn_mfma_f32_16x16x32_bf16(qf[dc], kf0, s0, 0, 0, 0);
                s1 = __builtin_amdgcn_mfma_f32_16x16x32_bf16(qf[dc], kf1, s1, 0, 0, 0);
            }
            const int key0 = kbase + (lane & 15);
            const int key1 = key0 + 16;
            float p0[4], p1[4], alpha[4];
            #pragma unroll
            for (int j = 0; j < 4; j++) {
                int qrow = q0 + (lane >> 4) * 4 + j;
                float sv0 = (key0 <= qrow) ? s0[j] * SM_SCALE : -INFINITY;
                float sv1 = (key1 <= qrow) ? s1[j] * SM_SCALE : -INFINITY;
                float mx = fmaxf(sv0, sv1);
                #pragma unroll
                for (int d = 1; d < 16; d <<= 1) mx = fmaxf(mx, __shfl_xor(mx, d));
                float mnew = fmaxf(m_run[j], mx);
                float a = expf(m_run[j] - mnew);     // first chunk: exp(-inf)=0
                p0[j] = expf(sv0 - mnew);
                p1[j] = expf(sv1 - mnew);
                float rs = p0[j] + p1[j];
                #pragma unroll
                for (int d = 1; d < 16; d <<= 1) rs += __shfl_xor(rs, d);
                l_run[j] = l_run[j] * a + rs;
                m_run[j] = mnew;
                alpha[j] = a;
            }
            #pragma unroll
            for (int nt = 0; nt < 8; nt++)
                #pragma unroll
                for (int j = 0; j < 4; j++) o[nt][j] *= alpha[j];
            #pragma unroll
            for (int j = 0; j < 4; j++) {
                int rloc = (lane >> 4) * 4 + j;
                Ps[wave][rloc * 40 + (lane & 15)]      = f2bf(p0[j]);
                Ps[wave][rloc * 40 + 16 + (lane & 15)] = f2bf(p1[j]);
            }
            bf16x8 pa = *(const bf16x8*)(&Ps[wave][(lane & 15) * 40 + (lane >> 4) * 8]);
            #pragma unroll
            for (int nt = 0; nt < 8; nt++) {
                bf16x8 vf = *(const bf16x8*)(&VsT[(nt * 16 + (lane & 15)) * 40 + (lane >> 4) * 8]);
                o[nt] = __builtin_amdgcn_mfma_f32_16x16x32_bf16(pa, vf, o[nt], 0, 0, 0);
            }
        }
    }

    #pragma unroll
    for (int j = 0; j < 4; j++) {
        float inv = 1.0f / l_run[j];
        size_t row = baseTok + q0 + (lane >> 4) * 4 + j;
        #pragma unroll
        for (int nt = 0; nt < 8; nt++)
            Ao[row * 512 + h * 128 + nt * 16 + (lane & 15)] = f2bf(o[nt][j] * inv);
    }
}

// ---------------------------------------------------------------------------
extern "C" void kernel_launch(void* const* d_in, const int* in_sizes, int n_in,
                              void* d_out, int out_size, void* d_ws, size_t ws_size,
                              hipStream_t stream) {
    const float* x     = (const float*)d_in[0];
    const float* Wq    = (const float*)d_in[1];
    const float* Wk    = (const float*)d_in[2];
    const float* bk    = (const float*)d_in[3];
    const float* Wv    = (const float*)d_in[4];
    const float* Wproj = (const float*)d_in[5];
    const float* bproj = (const float*)d_in[6];
    const float* w1    = (const float*)d_in[7];
    const float* w2    = (const float*)d_in[8];
    const float* Wi    = (const float*)d_in[9];
    const float* Wo    = (const float*)d_in[10];
    float* out = (float*)d_out;   // also serves as the f32 residual/z/x2 buffer
    (void)in_sizes; (void)n_in; (void)out_size;

    char* ws = (char*)d_ws;
    size_t off = 0;
    auto alloc = [&](size_t bytes) -> void* {
        void* p = ws + off;
        off += (bytes + 255) & ~(size_t)255;
        return p;
    };
    // ---- persistent weights (prepped once per call) ----
    ushort_t* WqkvT    = (ushort_t*)alloc((size_t)1536 * 512 * 2);
    float*    bias1536 = (float*)   alloc((size_t)1536 * 4);
    ushort_t* WprojT   = (ushort_t*)alloc((size_t)512 * 512 * 2);
    ushort_t* WiT      = (ushort_t*)alloc((size_t)4096 * 512 * 2);
    ushort_t* WoT2     = (ushort_t*)alloc((size_t)512 * 4096 * 2);
    const size_t weightBytes = off;

    // ---- choose batch-chunk count so scratch fits ws_size ----
    // per-chunk scratch: hb = Mc*512*2, big = Mc*4096*2 bytes
    int nchunks = 1;
    while (nchunks < 64) {
        size_t Mc = (size_t)TOKENS / nchunks;
        size_t need = weightBytes + Mc * 512 * 2 + Mc * 4096 * 2 + 4096;
        if (need <= ws_size) break;
        nchunks *= 2;
    }
    const size_t Mc = (size_t)TOKENS / nchunks;          // tokens per chunk
    const int    nbChunk = B_BATCH / nchunks;            // batches per chunk

    ushort_t* hb  = (ushort_t*)alloc(Mc * 512 * 2);      // h -> attn out -> x2 bf16 (time-shared)
    ushort_t* big = (ushort_t*)alloc(Mc * 4096 * 2);     // qkv (1536 wide) -> hmid (4096 wide)

    // ---- weight prep ----
    prep_qkv <<<(1536 * 512 + 255) / 256, 256, 0, stream>>>(Wq, Wk, Wv, WqkvT);
    prep_bias<<<6, 256, 0, stream>>>(bk, bias1536);
    prep_proj<<<1024, 256, 0, stream>>>(Wproj, WprojT);
    prep_wi  <<<8192, 256, 0, stream>>>(Wi, WiT);
    prep_wo  <<<8192, 256, 0, stream>>>(Wo, WoT2);

    for (int ck = 0; ck < nchunks; ck++) {
        const size_t t0 = (size_t)ck * Mc;
        const float* xC   = x + t0 * 512;
        float*       zC   = out + t0 * 512;
        const int    Mi   = (int)Mc;
        const int    mt   = Mi / 128;                    // M-tiles (multiple of 16)

        // h = rmsnorm(x, w1) -> hb (bf16)
        rmsnorm_kernel<0><<<Mi / 4, 256, 0, stream>>>(xC, w1, hb, nullptr);
        // QKV = h @ WqkvT^T + bias -> big (bf16, width 1536)
        gemm_kernel<0><<<mt * 12, 256, 0, stream>>>(
            hb, WqkvT, nullptr, big, bias1536, nullptr, 1536, 512);
        // attention -> hb (bf16, width 512)
        attn_kernel<<<dim3(T_SEQ / 64, nbChunk * H_HEADS), 256, 0, stream>>>(big, hb);
        // z = x + attn @ Wproj + bproj -> zC (f32, lives in d_out)
        gemm_kernel<1><<<mt * 4, 256, 0, stream>>>(
            hb, WprojT, zC, nullptr, bproj, xC, 512, 512);
        // x2 = rmsnorm(z, w2): bf16 -> hb, f32 in-place -> zC
        rmsnorm_kernel<1><<<Mi / 4, 256, 0, stream>>>(zC, w2, hb, zC);
        // hmid = gelu(x2 @ WiT^T), both branches as N=4096 -> big
        gemm_kernel<2><<<mt * 32, 256, 0, stream>>>(
            hb, WiT, nullptr, big, nullptr, nullptr, 4096, 512);
        // out = x2 + hmid @ WoT2^T   (0.5 folded into WoT2, K=4096)
        gemm_kernel<3><<<mt * 4, 256, 0, stream>>>(
            big, WoT2, zC, nullptr, nullptr, zC, 512, 4096);
    }
}

// Round 5
// 2866.730 us; speedup vs baseline: 1.2729x; 1.0963x over previous
//
#include <hip/hip_runtime.h>
#include <cstdint>
#include <cstddef>

#define TOKENS 131072      // B*T = 512*256
#define B_BATCH 512
#define T_SEQ 256
#define C_DIM 512
#define H_HEADS 4
#define HS_DIM 128
#define FF_DIM 2048
#define EPS_RMS 1e-8f
#define SM_SCALE 0.044194173824159216f   // 512^-0.5

typedef short bf16x8 __attribute__((ext_vector_type(8)));
typedef float f32x4 __attribute__((ext_vector_type(4)));
typedef unsigned short ushort_t;

__device__ __forceinline__ ushort_t f2bf(float f) {
    uint32_t u = __builtin_bit_cast(uint32_t, f);
    u += 0x7FFFu + ((u >> 16) & 1u);   // round-to-nearest-even
    return (ushort_t)(u >> 16);
}

__device__ __forceinline__ float gelu_exact(float v) {
    return 0.5f * v * (1.0f + erff(v * 0.70710678118654752f));
}

// async global->LDS, 16B/lane. Dest must be wave-uniform; HW adds lane*16.
__device__ __forceinline__ void stage8k(ushort_t* lds, const ushort_t* g) {
    __builtin_amdgcn_global_load_lds(
        (const __attribute__((address_space(1))) uint32_t*)g,
        (__attribute__((address_space(3))) uint32_t*)lds,
        16, 0, 0);
}

// ---------------------------------------------------------------------------
// Weight prep: fp32 -> bf16, transposed to N x K row-major
// ---------------------------------------------------------------------------
__global__ void prep_qkv(const float* __restrict__ Wq, const float* __restrict__ Wk,
                         const float* __restrict__ Wv, ushort_t* __restrict__ WqkvT) {
    int idx = blockIdx.x * 256 + threadIdx.x;       // over 1536*512
    if (idx >= 1536 * 512) return;
    int n = idx >> 9;
    int k = idx & 511;
    int h = (n & 511) >> 7;
    int d = n & 127;
    float v;
    size_t s = ((size_t)h * 512 + k) * 128 + d;     // (H,C,HS)
    if (n < 512)       v = Wq[s];
    else if (n < 1024) v = Wk[s];
    else               v = Wv[s];
    WqkvT[idx] = f2bf(v);
}

__global__ void prep_bias(const float* __restrict__ bk, float* __restrict__ bias1536) {
    int n = blockIdx.x * 256 + threadIdx.x;
    if (n >= 1536) return;
    bias1536[n] = (n >= 512 && n < 1024) ? bk[n - 512] : 0.0f;   // bk flat (H,HS)
}

__global__ void prep_proj(const float* __restrict__ Wproj, ushort_t* __restrict__ WprojT) {
    int idx = blockIdx.x * 256 + threadIdx.x;       // over 512*512
    if (idx >= 512 * 512) return;
    int n = idx >> 9, k = idx & 511;
    WprojT[idx] = f2bf(Wproj[(size_t)k * 512 + n]);
}

__global__ void prep_wi(const float* __restrict__ Wi, ushort_t* __restrict__ WiT) {
    int idx = blockIdx.x * 256 + threadIdx.x;       // over 2*2048*512
    if (idx >= 2 * 2048 * 512) return;
    int b = idx >> 20;
    int rem = idx & 1048575;
    int f = rem >> 9, c = rem & 511;                // WiT[b*2048+f][c] = [4096][512]
    WiT[idx] = f2bf(Wi[((size_t)b * 512 + c) * 2048 + f]);
}

// WoT2[c][br*2048+f] = 0.5 * Wo[br][f][c]  -> [512][4096] row-major over K=4096
__global__ void prep_wo(const float* __restrict__ Wo, ushort_t* __restrict__ WoT2) {
    int idx = blockIdx.x * 256 + threadIdx.x;       // over 512*4096
    if (idx >= 512 * 4096) return;
    int c  = idx >> 12;
    int n2 = idx & 4095;
    int br = n2 >> 11;
    int f  = n2 & 2047;
    WoT2[idx] = f2bf(0.5f * Wo[(((size_t)br * 2048 + f) * 512) + c]);
}

// ---------------------------------------------------------------------------
// RMSNorm: one wave per token (512 floats, 8/lane)
// ---------------------------------------------------------------------------
template<int WRITE_F32>
__global__ __launch_bounds__(256) void rmsnorm_kernel(const float* __restrict__ in,
                                                      const float* __restrict__ wptr,
                                                      ushort_t* __restrict__ outb,
                                                      float* outf) {
    const int lane = threadIdx.x & 63;
    const int wave = threadIdx.x >> 6;
    const size_t token = (size_t)blockIdx.x * 4 + wave;
    const float* row = in + token * 512;
    float4 v0 = *(const float4*)(row + lane * 8);
    float4 v1 = *(const float4*)(row + lane * 8 + 4);
    float ss = v0.x*v0.x + v0.y*v0.y + v0.z*v0.z + v0.w*v0.w
             + v1.x*v1.x + v1.y*v1.y + v1.z*v1.z + v1.w*v1.w;
    #pragma unroll
    for (int d = 32; d; d >>= 1) ss += __shfl_xor(ss, d);
    float scale = wptr[0] * rsqrtf(ss * (1.0f / 512.0f) + EPS_RMS);
    float vals[8] = {v0.x, v0.y, v0.z, v0.w, v1.x, v1.y, v1.z, v1.w};
    union { ushort_t us[8]; uint4 u4; } pk;
    #pragma unroll
    for (int i = 0; i < 8; i++) pk.us[i] = f2bf(vals[i] * scale);
    *(uint4*)(outb + token * 512 + lane * 8) = pk.u4;
    if (WRITE_F32) {
        float4 o0 = make_float4(v0.x*scale, v0.y*scale, v0.z*scale, v0.w*scale);
        float4 o1 = make_float4(v1.x*scale, v1.y*scale, v1.z*scale, v1.w*scale);
        *(float4*)(outf + token * 512 + lane * 8)     = o0;
        *(float4*)(outf + token * 512 + lane * 8 + 4) = o1;
    }
}

// ---------------------------------------------------------------------------
// GEMM 256x256, 8-phase counted-vmcnt schedule (T3+T4+T5), BK=32, 2 LDS bufs.
// C[M,N] = A[M,K] * Bt[N,K]^T  (bf16, row-major over K).
// 8 waves (2M x 4N); per-wave C = 128x64 (8x4 frags of 16x16); 8 MFMA/phase.
// Buffers: S[buf][op][256*32]; buf0 = even K-tiles, buf1 = odd. Per phase:
// {ds_read frag subtile | stage 1 half-tile (global_load_lds) | setprio(1)
//  8 MFMA setprio(0) | lgkmcnt(0) | [P4/P8: vmcnt(3)] | raw s_barrier}.
// Hand-verified schedule (stage region is free, and every use is covered by
// a vmcnt(3)+barrier that precedes it):
//   P1 stage B.p0->t+1 | P2 A.p0->t+2 | P3 B.p1->t+2 | P4 A.p1->t+2 +vmcnt
//   P5 stage B.p0->t+2 | P6 A.p0->t+3 | P7 B.p1->t+3 | P8 A.p1->t+3 +vmcnt
// Tail stages clamp the SOURCE tile only (dest buffer stays schedule-correct).
// MODE 0: Cb = bf16(acc + bias[c])       MODE 1: Cf = acc + bias[c] + X
// MODE 2: Cb = bf16(gelu(acc))           MODE 3: Cf = X + acc
// ---------------------------------------------------------------------------
template<int MODE>
__global__ __launch_bounds__(512) void gemm256(
    const ushort_t* __restrict__ A, const ushort_t* __restrict__ Bt,
    float* Cf, ushort_t* __restrict__ Cb,
    const float* __restrict__ bias, const float* __restrict__ X,
    int N, int K)
{
    __shared__ __align__(16) ushort_t S[2][2][8192];   // [buf][0=A,1=B][256*32]
    const int tid  = threadIdx.x;
    const int lane = tid & 63;
    const int wave = tid >> 6;
    const int wm = wave >> 2;          // 0..1
    const int wn = wave & 3;           // 0..3

    // XCD-chunked bijective swizzle (nwg % 8 == 0 for all our grids)
    const int nwg  = (int)gridDim.x;
    const int orig = (int)blockIdx.x;
    const int wgid = (orig & 7) * (nwg >> 3) + (orig >> 3);
    const int gx   = N >> 8;
    const int bm = (wgid / gx) << 8;
    const int bn = (wgid % gx) << 8;

    const int NT = K >> 5;             // K-tiles of 32 (always even here)

    // staging geometry: one issue = 512 lanes x 16B = 8KB = one half-tile.
    // A part p covers rows {bit6==p within each 128-block}: rows
    //   (wave>>2)*128 + p*64 + (wave&3)*16 + (lane>>2)
    // B part p covers rows {bit5==p within each 64-block}: rows
    //   (wave>>1)*64 + p*32 + (wave&1)*16 + (lane>>2)
    // LDS dest (wave-uniform; HW adds lane*16B which equals (lane>>2)*32+(lane&3)*8 elems)
    const int srowA  = (wave >> 2) * 128 + (wave & 3) * 16 + (lane >> 2);
    const int sbaseA = ((wave >> 2) * 128 + (wave & 3) * 16) * 32;
    const int srowB  = (wave >> 1) * 64 + (wave & 1) * 16 + (lane >> 2);
    const int sbaseB = ((wave >> 1) * 64 + (wave & 1) * 16) * 32;
    const int scol   = (lane & 3) * 8;

    auto stA = [&](int dbuf, int part, int ts) {
        int tc = ts < NT ? ts : NT - 1;
        stage8k(&S[dbuf][0][sbaseA + part * 2048],
                A + (size_t)(bm + srowA + part * 64) * K + tc * 32 + scol);
    };
    auto stB = [&](int dbuf, int part, int ts) {
        int tc = ts < NT ? ts : NT - 1;
        stage8k(&S[dbuf][1][sbaseB + part * 1024],
                Bt + (size_t)(bn + srowB + part * 32) * K + tc * 32 + scol);
    };

    const int q8  = (lane >> 4) * 8;
    const int r16 = lane & 15;

    f32x4 acc[8][4] = {};
    bf16x8 a[4], b0[2], b1[2];

#define LDA(BUF, MH) { \
    _Pragma("unroll") for (int mf = 0; mf < 4; mf++) \
        a[mf] = *(const bf16x8*)&S[BUF][0][(wm*128 + (MH)*64 + mf*16 + r16)*32 + q8]; }
#define LDB(BUF, NH, breg) { \
    _Pragma("unroll") for (int nf = 0; nf < 2; nf++) \
        breg[nf] = *(const bf16x8*)&S[BUF][1][(wn*64 + (NH)*32 + nf*16 + r16)*32 + q8]; }
#define MM(MH, NH, breg) { \
    __builtin_amdgcn_s_setprio(1); \
    _Pragma("unroll") for (int mf = 0; mf < 4; mf++) \
    _Pragma("unroll") for (int nf = 0; nf < 2; nf++) \
        acc[(MH)*4+mf][(NH)*2+nf] = __builtin_amdgcn_mfma_f32_16x16x32_bf16( \
            a[mf], breg[nf], acc[(MH)*4+mf][(NH)*2+nf], 0, 0, 0); \
    __builtin_amdgcn_s_setprio(0); }
#define ENDPH  { asm volatile("s_waitcnt lgkmcnt(0)" ::: "memory"); __builtin_amdgcn_s_barrier(); }
#define ENDPHV { asm volatile("s_waitcnt lgkmcnt(0)\n\ts_waitcnt vmcnt(3)" ::: "memory"); __builtin_amdgcn_s_barrier(); }

    // prologue: tile0 complete (4 stages), then 3 of tile1 (B.p0(1) comes at P1)
    stA(0, 0, 0); stB(0, 0, 0); stB(0, 1, 0); stA(0, 1, 0);
    stA(1, 0, 1); stB(1, 1, 1); stA(1, 1, 1);
    asm volatile("s_waitcnt vmcnt(3)" ::: "memory");
    __builtin_amdgcn_s_barrier();

    const int NI = NT >> 1;
    for (int I = 0; I < NI; ++I) {
        const int t = 2 * I;
        // ---- K-tile t (buf0) ----
        LDA(0,0); LDB(0,0,b0);  stB(1, 0, t+1);  MM(0,0,b0);  ENDPH;   // P1 Q(0,0)
        LDB(0,1,b1);            stA(0, 0, t+2);  MM(0,1,b1);  ENDPH;   // P2 Q(0,1)
        LDA(0,1);               stB(0, 1, t+2);  MM(1,1,b1);  ENDPH;   // P3 Q(1,1)
                                stA(0, 1, t+2);  MM(1,0,b0);  ENDPHV;  // P4 Q(1,0)
        // ---- K-tile t+1 (buf1) ----
        LDA(1,0); LDB(1,0,b0);  stB(0, 0, t+2);  MM(0,0,b0);  ENDPH;   // P5
        LDB(1,1,b1);            stA(1, 0, t+3);  MM(0,1,b1);  ENDPH;   // P6
        LDA(1,1);               stB(1, 1, t+3);  MM(1,1,b1);  ENDPH;   // P7
                                stA(1, 1, t+3);  MM(1,0,b0);  ENDPHV;  // P8
    }
#undef LDA
#undef LDB
#undef MM
#undef ENDPH
#undef ENDPHV

    #pragma unroll
    for (int mf = 0; mf < 8; mf++) {
        #pragma unroll
        for (int nf = 0; nf < 4; nf++) {
            #pragma unroll
            for (int j = 0; j < 4; j++) {
                int r = bm + wm * 128 + mf * 16 + (lane >> 4) * 4 + j;
                int c = bn + wn * 64 + nf * 16 + r16;
                float v = acc[mf][nf][j];
                size_t idx = (size_t)r * N + c;
                if (MODE == 0)      { Cb[idx] = f2bf(v + bias[c]); }
                else if (MODE == 1) { Cf[idx] = v + bias[c] + X[idx]; }
                else if (MODE == 2) { Cb[idx] = f2bf(gelu_exact(v)); }
                else                { Cf[idx] = X[idx] + v; }
            }
        }
    }
}

// ---------------------------------------------------------------------------
// Fused causal attention, flash-style (online softmax). Unchanged from r4.
// ---------------------------------------------------------------------------
__global__ __launch_bounds__(256) void attn_kernel(const ushort_t* __restrict__ QKV,
                                                   ushort_t* __restrict__ Ao) {
    __shared__ __align__(16) ushort_t Ks[32 * 136];
    __shared__ __align__(16) ushort_t VsT[128 * 40];
    __shared__ __align__(16) ushort_t Ps[4][16 * 40];
    const int tid  = threadIdx.x;
    const int lane = tid & 63;
    const int wave = tid >> 6;
    const int qtile = blockIdx.x;                 // 0..3
    const int bh = blockIdx.y;                    // local_b * 4 + h
    const int b = bh >> 2;
    const int h = bh & 3;
    const int qb = qtile * 64;
    const int q0 = qb + wave * 16;
    const size_t baseTok = (size_t)b * T_SEQ;

    bf16x8 qf[4];
    {
        const ushort_t* qrow = QKV + (baseTok + q0 + (lane & 15)) * 1536 + h * 128 + (lane >> 4) * 8;
        #pragma unroll
        for (int dc = 0; dc < 4; dc++)
            qf[dc] = *(const bf16x8*)(qrow + dc * 32);
    }

    float m_run[4], l_run[4];
    f32x4 o[8];
    #pragma unroll
    for (int j = 0; j < 4; j++) { m_run[j] = -INFINITY; l_run[j] = 0.0f; }
    #pragma unroll
    for (int nt = 0; nt < 8; nt++) o[nt] = f32x4{0.f, 0.f, 0.f, 0.f};

    const int nchunks = qtile * 2 + 2;
    for (int kc = 0; kc < nchunks; kc++) {
        const int kbase = kc * 32;
        __syncthreads();
        #pragma unroll
        for (int r = 0; r < 2; r++) {
            int li = r * 256 + tid;
            int row = li >> 4;               // 0..31 key within chunk
            int c8 = (li & 15) * 8;          // 0..120 d
            size_t g = (baseTok + kbase + row) * 1536;
            uint4 vk = *(const uint4*)(QKV + g + 512 + h * 128 + c8);
            *(uint4*)(&Ks[row * 136 + c8]) = vk;
            uint4 vv = *(const uint4*)(QKV + g + 1024 + h * 128 + c8);
            ushort_t* pv = (ushort_t*)&vv;
            #pragma unroll
            for (int jj = 0; jj < 8; jj++)
                VsT[(c8 + jj) * 40 + row] = pv[jj];
        }
        __syncthreads();

        if (q0 + 15 >= kbase) {
            f32x4 s0 = {0.f,0.f,0.f,0.f}, s1 = {0.f,0.f,0.f,0.f};
            #pragma unroll
            for (int dc = 0; dc < 4; dc++) {
                bf16x8 kf0 = *(const bf16x8*)(&Ks[(lane & 15) * 136 + dc * 32 + (lane >> 4) * 8]);
                bf16x8 kf1 = *(const bf16x8*)(&Ks[(16 + (lane & 15)) * 136 + dc * 32 + (lane >> 4) * 8]);
                s0 = __builtin_amdgcn_mfma_f32_16x16x32_bf16(qf[dc], kf0, s0, 0, 0, 0);
                s1 = __builtin_amdgcn_mfma_f32_16x16x32_bf16(qf[dc], kf1, s1, 0, 0, 0);
            }
            const int key0 = kbase + (lane & 15);
            const int key1 = key0 + 16;
            float p0[4], p1[4], alpha[4];
            #pragma unroll
            for (int j = 0; j < 4; j++) {
                int qrow = q0 + (lane >> 4) * 4 + j;
                float sv0 = (key0 <= qrow) ? s0[j] * SM_SCALE : -INFINITY;
                float sv1 = (key1 <= qrow) ? s1[j] * SM_SCALE : -INFINITY;
                float mx = fmaxf(sv0, sv1);
                #pragma unroll
                for (int d = 1; d < 16; d <<= 1) mx = fmaxf(mx, __shfl_xor(mx, d));
                float mnew = fmaxf(m_run[j], mx);
                float aa = expf(m_run[j] - mnew);
                p0[j] = expf(sv0 - mnew);
                p1[j] = expf(sv1 - mnew);
                float rs = p0[j] + p1[j];
                #pragma unroll
                for (int d = 1; d < 16; d <<= 1) rs += __shfl_xor(rs, d);
                l_run[j] = l_run[j] * aa + rs;
                m_run[j] = mnew;
                alpha[j] = aa;
            }
            #pragma unroll
            for (int nt = 0; nt < 8; nt++)
                #pragma unroll
                for (int j = 0; j < 4; j++) o[nt][j] *= alpha[j];
            #pragma unroll
            for (int j = 0; j < 4; j++) {
                int rloc = (lane >> 4) * 4 + j;
                Ps[wave][rloc * 40 + (lane & 15)]      = f2bf(p0[j]);
                Ps[wave][rloc * 40 + 16 + (lane & 15)] = f2bf(p1[j]);
            }
            bf16x8 pa = *(const bf16x8*)(&Ps[wave][(lane & 15) * 40 + (lane >> 4) * 8]);
            #pragma unroll
            for (int nt = 0; nt < 8; nt++) {
                bf16x8 vf = *(const bf16x8*)(&VsT[(nt * 16 + (lane & 15)) * 40 + (lane >> 4) * 8]);
                o[nt] = __builtin_amdgcn_mfma_f32_16x16x32_bf16(pa, vf, o[nt], 0, 0, 0);
            }
        }
    }

    #pragma unroll
    for (int j = 0; j < 4; j++) {
        float inv = 1.0f / l_run[j];
        size_t row = baseTok + q0 + (lane >> 4) * 4 + j;
        #pragma unroll
        for (int nt = 0; nt < 8; nt++)
            Ao[row * 512 + h * 128 + nt * 16 + (lane & 15)] = f2bf(o[nt][j] * inv);
    }
}

// ---------------------------------------------------------------------------
extern "C" void kernel_launch(void* const* d_in, const int* in_sizes, int n_in,
                              void* d_out, int out_size, void* d_ws, size_t ws_size,
                              hipStream_t stream) {
    const float* x     = (const float*)d_in[0];
    const float* Wq    = (const float*)d_in[1];
    const float* Wk    = (const float*)d_in[2];
    const float* bk    = (const float*)d_in[3];
    const float* Wv    = (const float*)d_in[4];
    const float* Wproj = (const float*)d_in[5];
    const float* bproj = (const float*)d_in[6];
    const float* w1    = (const float*)d_in[7];
    const float* w2    = (const float*)d_in[8];
    const float* Wi    = (const float*)d_in[9];
    const float* Wo    = (const float*)d_in[10];
    float* out = (float*)d_out;   // also serves as the f32 residual/z/x2 buffer
    (void)in_sizes; (void)n_in; (void)out_size;

    char* ws = (char*)d_ws;
    size_t off = 0;
    auto alloc = [&](size_t bytes) -> void* {
        void* p = ws + off;
        off += (bytes + 255) & ~(size_t)255;
        return p;
    };
    // ---- persistent weights (prepped once per call) ----
    ushort_t* WqkvT    = (ushort_t*)alloc((size_t)1536 * 512 * 2);
    float*    bias1536 = (float*)   alloc((size_t)1536 * 4);
    ushort_t* WprojT   = (ushort_t*)alloc((size_t)512 * 512 * 2);
    ushort_t* WiT      = (ushort_t*)alloc((size_t)4096 * 512 * 2);
    ushort_t* WoT2     = (ushort_t*)alloc((size_t)512 * 4096 * 2);
    const size_t weightBytes = off;

    // ---- choose batch-chunk count so scratch fits ws_size ----
    int nchunks = 1;
    while (nchunks < 64) {
        size_t Mc = (size_t)TOKENS / nchunks;
        size_t need = weightBytes + Mc * 512 * 2 + Mc * 4096 * 2 + 4096;
        if (need <= ws_size) break;
        nchunks *= 2;
    }
    const size_t Mc = (size_t)TOKENS / nchunks;          // tokens per chunk
    const int    nbChunk = B_BATCH / nchunks;            // batches per chunk

    ushort_t* hb  = (ushort_t*)alloc(Mc * 512 * 2);      // h -> attn out -> x2 bf16 (time-shared)
    ushort_t* big = (ushort_t*)alloc(Mc * 4096 * 2);     // qkv (1536 wide) -> hmid (4096 wide)

    // ---- weight prep ----
    prep_qkv <<<(1536 * 512 + 255) / 256, 256, 0, stream>>>(Wq, Wk, Wv, WqkvT);
    prep_bias<<<6, 256, 0, stream>>>(bk, bias1536);
    prep_proj<<<1024, 256, 0, stream>>>(Wproj, WprojT);
    prep_wi  <<<8192, 256, 0, stream>>>(Wi, WiT);
    prep_wo  <<<8192, 256, 0, stream>>>(Wo, WoT2);

    for (int ck = 0; ck < nchunks; ck++) {
        const size_t t0 = (size_t)ck * Mc;
        const float* xC   = x + t0 * 512;
        float*       zC   = out + t0 * 512;
        const int    Mi   = (int)Mc;
        const int    mt   = Mi / 256;                    // 256-row M-tiles

        // h = rmsnorm(x, w1) -> hb (bf16)
        rmsnorm_kernel<0><<<Mi / 4, 256, 0, stream>>>(xC, w1, hb, nullptr);
        // QKV = h @ WqkvT^T + bias -> big (bf16, width 1536)
        gemm256<0><<<mt * 6, 512, 0, stream>>>(
            hb, WqkvT, nullptr, big, bias1536, nullptr, 1536, 512);
        // attention -> hb (bf16, width 512)
        attn_kernel<<<dim3(T_SEQ / 64, nbChunk * H_HEADS), 256, 0, stream>>>(big, hb);
        // z = x + attn @ Wproj + bproj -> zC (f32, lives in d_out)
        gemm256<1><<<mt * 2, 512, 0, stream>>>(
            hb, WprojT, zC, nullptr, bproj, xC, 512, 512);
        // x2 = rmsnorm(z, w2): bf16 -> hb, f32 in-place -> zC
        rmsnorm_kernel<1><<<Mi / 4, 256, 0, stream>>>(zC, w2, hb, zC);
        // hmid = gelu(x2 @ WiT^T), both branches as N=4096 -> big
        gemm256<2><<<mt * 16, 512, 0, stream>>>(
            hb, WiT, nullptr, big, nullptr, nullptr, 4096, 512);
        // out = x2 + hmid @ WoT2^T   (0.5 folded into WoT2, K=4096)
        gemm256<3><<<mt * 2, 512, 0, stream>>>(
            big, WoT2, zC, nullptr, nullptr, zC, 512, 4096);
    }
}

// Round 6
// 2705.966 us; speedup vs baseline: 1.3485x; 1.0594x over previous
//
#include <hip/hip_runtime.h>
#include <cstdint>
#include <cstddef>

#define TOKENS 131072      // B*T = 512*256
#define B_BATCH 512
#define T_SEQ 256
#define C_DIM 512
#define H_HEADS 4
#define HS_DIM 128
#define FF_DIM 2048
#define EPS_RMS 1e-8f
#define SM_SCALE 0.044194173824159216f   // 512^-0.5

typedef short bf16x8 __attribute__((ext_vector_type(8)));
typedef float f32x4 __attribute__((ext_vector_type(4)));
typedef unsigned short ushort_t;

__device__ __forceinline__ ushort_t f2bf(float f) {
    uint32_t u = __builtin_bit_cast(uint32_t, f);
    u += 0x7FFFu + ((u >> 16) & 1u);   // round-to-nearest-even
    return (ushort_t)(u >> 16);
}

__device__ __forceinline__ float gelu_exact(float v) {
    return 0.5f * v * (1.0f + erff(v * 0.70710678118654752f));
}

// async global->LDS, 16B/lane. Dest must be wave-uniform; HW adds lane*16.
__device__ __forceinline__ void stage8k(ushort_t* lds, const ushort_t* g) {
    __builtin_amdgcn_global_load_lds(
        (const __attribute__((address_space(1))) uint32_t*)g,
        (__attribute__((address_space(3))) uint32_t*)lds,
        16, 0, 0);
}

// ---------------------------------------------------------------------------
// Weight prep: fp32 -> bf16, transposed to N x K row-major
// ---------------------------------------------------------------------------
__global__ void prep_qkv(const float* __restrict__ Wq, const float* __restrict__ Wk,
                         const float* __restrict__ Wv, ushort_t* __restrict__ WqkvT) {
    int idx = blockIdx.x * 256 + threadIdx.x;       // over 1536*512
    if (idx >= 1536 * 512) return;
    int n = idx >> 9;
    int k = idx & 511;
    int h = (n & 511) >> 7;
    int d = n & 127;
    float v;
    size_t s = ((size_t)h * 512 + k) * 128 + d;     // (H,C,HS)
    if (n < 512)       v = Wq[s];
    else if (n < 1024) v = Wk[s];
    else               v = Wv[s];
    WqkvT[idx] = f2bf(v);
}

__global__ void prep_bias(const float* __restrict__ bk, float* __restrict__ bias1536) {
    int n = blockIdx.x * 256 + threadIdx.x;
    if (n >= 1536) return;
    bias1536[n] = (n >= 512 && n < 1024) ? bk[n - 512] : 0.0f;   // bk flat (H,HS)
}

__global__ void prep_proj(const float* __restrict__ Wproj, ushort_t* __restrict__ WprojT) {
    int idx = blockIdx.x * 256 + threadIdx.x;       // over 512*512
    if (idx >= 512 * 512) return;
    int n = idx >> 9, k = idx & 511;
    WprojT[idx] = f2bf(Wproj[(size_t)k * 512 + n]);
}

__global__ void prep_wi(const float* __restrict__ Wi, ushort_t* __restrict__ WiT) {
    int idx = blockIdx.x * 256 + threadIdx.x;       // over 2*2048*512
    if (idx >= 2 * 2048 * 512) return;
    int b = idx >> 20;
    int rem = idx & 1048575;
    int f = rem >> 9, c = rem & 511;                // WiT[b*2048+f][c] = [4096][512]
    WiT[idx] = f2bf(Wi[((size_t)b * 512 + c) * 2048 + f]);
}

// WoT2[c][br*2048+f] = 0.5 * Wo[br][f][c]  -> [512][4096] row-major over K=4096
__global__ void prep_wo(const float* __restrict__ Wo, ushort_t* __restrict__ WoT2) {
    int idx = blockIdx.x * 256 + threadIdx.x;       // over 512*4096
    if (idx >= 512 * 4096) return;
    int c  = idx >> 12;
    int n2 = idx & 4095;
    int br = n2 >> 11;
    int f  = n2 & 2047;
    WoT2[idx] = f2bf(0.5f * Wo[(((size_t)br * 2048 + f) * 512) + c]);
}

// ---------------------------------------------------------------------------
// RMSNorm: one wave per token (512 floats, 8/lane)
// ---------------------------------------------------------------------------
template<int WRITE_F32>
__global__ __launch_bounds__(256) void rmsnorm_kernel(const float* __restrict__ in,
                                                      const float* __restrict__ wptr,
                                                      ushort_t* __restrict__ outb,
                                                      float* outf) {
    const int lane = threadIdx.x & 63;
    const int wave = threadIdx.x >> 6;
    const size_t token = (size_t)blockIdx.x * 4 + wave;
    const float* row = in + token * 512;
    float4 v0 = *(const float4*)(row + lane * 8);
    float4 v1 = *(const float4*)(row + lane * 8 + 4);
    float ss = v0.x*v0.x + v0.y*v0.y + v0.z*v0.z + v0.w*v0.w
             + v1.x*v1.x + v1.y*v1.y + v1.z*v1.z + v1.w*v1.w;
    #pragma unroll
    for (int d = 32; d; d >>= 1) ss += __shfl_xor(ss, d);
    float scale = wptr[0] * rsqrtf(ss * (1.0f / 512.0f) + EPS_RMS);
    float vals[8] = {v0.x, v0.y, v0.z, v0.w, v1.x, v1.y, v1.z, v1.w};
    union { ushort_t us[8]; uint4 u4; } pk;
    #pragma unroll
    for (int i = 0; i < 8; i++) pk.us[i] = f2bf(vals[i] * scale);
    *(uint4*)(outb + token * 512 + lane * 8) = pk.u4;
    if (WRITE_F32) {
        float4 o0 = make_float4(v0.x*scale, v0.y*scale, v0.z*scale, v0.w*scale);
        float4 o1 = make_float4(v1.x*scale, v1.y*scale, v1.z*scale, v1.w*scale);
        *(float4*)(outf + token * 512 + lane * 8)     = o0;
        *(float4*)(outf + token * 512 + lane * 8 + 4) = o1;
    }
}

// ---------------------------------------------------------------------------
// GEMM 256x256, BK=64, 8-phase counted-vmcnt (T2+T3+T4+T5), 128KB LDS.
// C[M,N] = A[M,K] * Bt[N,K]^T  (bf16, row-major over K).
// 8 waves (2M x 4N); per-wave C = 128x64; 16 MFMA per phase (one quadrant
// (MH,NH) x K=64). LDS [buf][op][256 rows][64 elems], 16B-granule swizzle:
//   LDS(row, slot) holds global granule (slot ^ (row&7)) of that row.
// Staged with linear LDS dest + pre-swizzled global src (src col granule =
// (lane&7) ^ (lane>>3), lane-constant since staged row == lane>>3 mod 8).
// Reads: slot = g ^ (lane&7); each 16-lane group -> 2 lanes/slot = free.
// Stage ledger (1 part = half an operand tile = 2 issues, per phase):
//   P1:A1(t+1)->b1  P2:B0(t+1)->b1  P3:A0(t+2)->b0  P4:B1(t+2)->b0 +vmcnt(4)
//   P5:A1(t+2)->b0  P6:B0(t+2)->b0  P7:A0(t+3)->b1  P8:B1(t+3)->b1 +vmcnt(4)
// Quadrant order (0,0),(0,1),(1,1),(1,0): every write is after its part's
// last read; every first-read is behind a vmcnt(4)+barrier. Tail clamps the
// SOURCE tile; clamped writes land in parts never read again.
// MODE 0: Cb = bf16(acc + bias[c])       MODE 1: Cf = acc + bias[c] + X
// MODE 2: Cb = bf16(gelu(acc))           MODE 3: Cf = X + acc
// ---------------------------------------------------------------------------
template<int MODE>
__global__ __launch_bounds__(512) void gemm256(
    const ushort_t* __restrict__ A, const ushort_t* __restrict__ Bt,
    float* Cf, ushort_t* __restrict__ Cb,
    const float* __restrict__ bias, const float* __restrict__ X,
    int N, int K)
{
    __shared__ __align__(16) ushort_t S[2][2][256 * 64];   // [buf][0=A,1=B] 128KB
    const int tid  = threadIdx.x;
    const int lane = tid & 63;
    const int wave = tid >> 6;
    const int wm = wave >> 2;          // 0..1
    const int wn = wave & 3;           // 0..3

    // XCD-chunked bijective swizzle (nwg % 8 == 0 for all our grids)
    const int nwg  = (int)gridDim.x;
    const int orig = (int)blockIdx.x;
    const int wgid = (orig & 7) * (nwg >> 3) + (orig >> 3);
    const int gx   = N >> 8;
    const int bm = (wgid / gx) << 8;
    const int bn = (wgid % gx) << 8;

    const int NT = K >> 6;             // K-tiles of 64 (NT >= 8, even, here)

    // pre-swizzled global source column (elements): granule (lane&7)^(lane>>3)
    const int sx = (((lane & 7) ^ (lane >> 3)) << 3);

    // A part p = rows with bit6==p; issue i covers contiguous rows
    // [i*128 + p*64, +64); wave w stages rows +w*8+(lane>>3). row&7 == lane>>3.
    auto stA = [&](int dbuf, int part, int ts) {
        int tc = ts < NT ? ts : NT - 1;
        #pragma unroll
        for (int i = 0; i < 2; i++) {
            int rbase = i * 128 + part * 64 + wave * 8;
            stage8k(&S[dbuf][0][rbase * 64],
                    A + (size_t)(bm + rbase + (lane >> 3)) * K + tc * 64 + sx);
        }
    };
    // B part p = rows with bit5==p; issue i covers chunks {i*128, i*128+64};
    // wave w: chunk (w>>2), sub-block (w&3)*8. row&7 == lane>>3.
    auto stB = [&](int dbuf, int part, int ts) {
        int tc = ts < NT ? ts : NT - 1;
        #pragma unroll
        for (int i = 0; i < 2; i++) {
            int rbase = i * 128 + (wave >> 2) * 64 + part * 32 + (wave & 3) * 8;
            stage8k(&S[dbuf][1][rbase * 64],
                    Bt + (size_t)(bn + rbase + (lane >> 3)) * K + tc * 64 + sx);
        }
    };

    const int r16 = lane & 15;
    const int l7  = lane & 7;
    const int q   = lane >> 4;
    const int ge0 = ((q)     ^ l7) << 3;   // k-slice 0 granule elems
    const int ge1 = ((4 + q) ^ l7) << 3;   // k-slice 1

    f32x4 acc[8][4] = {};
    bf16x8 a[4][2], b[2][2];

#define LDA(BUF, MH) { _Pragma("unroll") for (int mf = 0; mf < 4; mf++) { \
    int R = wm * 128 + (MH) * 64 + mf * 16 + r16; \
    a[mf][0] = *(const bf16x8*)&S[BUF][0][R * 64 + ge0]; \
    a[mf][1] = *(const bf16x8*)&S[BUF][0][R * 64 + ge1]; } }
#define LDB(BUF, NH) { _Pragma("unroll") for (int nf = 0; nf < 2; nf++) { \
    int R = wn * 64 + (NH) * 32 + nf * 16 + r16; \
    b[nf][0] = *(const bf16x8*)&S[BUF][1][R * 64 + ge0]; \
    b[nf][1] = *(const bf16x8*)&S[BUF][1][R * 64 + ge1]; } }
#define MM(MH, NH) { __builtin_amdgcn_s_setprio(1); \
    _Pragma("unroll") for (int mf = 0; mf < 4; mf++) \
    _Pragma("unroll") for (int nf = 0; nf < 2; nf++) { \
        f32x4 t0 = __builtin_amdgcn_mfma_f32_16x16x32_bf16(a[mf][0], b[nf][0], acc[(MH)*4+mf][(NH)*2+nf], 0, 0, 0); \
        acc[(MH)*4+mf][(NH)*2+nf] = __builtin_amdgcn_mfma_f32_16x16x32_bf16(a[mf][1], b[nf][1], t0, 0, 0, 0); } \
    __builtin_amdgcn_s_setprio(0); }
#define BAR    __builtin_amdgcn_s_barrier()
#define WAITL  { asm volatile("s_waitcnt lgkmcnt(0)" ::: "memory"); __builtin_amdgcn_sched_barrier(0); }
#define WAITLV { asm volatile("s_waitcnt lgkmcnt(0)\n\ts_waitcnt vmcnt(4)" ::: "memory"); __builtin_amdgcn_sched_barrier(0); }

    // prologue: tile0 full (buf0), tile1 {A0, B1} (buf1) = 12 issues;
    // vmcnt(4) -> tile0 confirmed, tile1 partials may stay in flight.
    stA(0, 0, 0); stA(0, 1, 0); stB(0, 0, 0); stB(0, 1, 0);
    stA(1, 0, 1); stB(1, 1, 1);
    asm volatile("s_waitcnt vmcnt(4)" ::: "memory");
    __builtin_amdgcn_sched_barrier(0);
    BAR;

    const int NI = NT >> 1;
    for (int I = 0; I < NI; ++I) {
        const int t = 2 * I;
        // ---- K-tile t (buf0) ----
        LDA(0, 0); LDB(0, 0);  stA(1, 1, t + 1);  BAR; WAITL;  MM(0, 0); BAR;  // P1
        LDB(0, 1);             stB(1, 0, t + 1);  BAR; WAITL;  MM(0, 1); BAR;  // P2
        LDA(0, 1);             stA(0, 0, t + 2);  BAR; WAITL;  MM(1, 1); BAR;  // P3
        LDB(0, 0);             stB(0, 1, t + 2);  BAR; WAITLV; MM(1, 0); BAR;  // P4
        // ---- K-tile t+1 (buf1) ----
        LDA(1, 0); LDB(1, 0);  stA(0, 1, t + 2);  BAR; WAITL;  MM(0, 0); BAR;  // P5
        LDB(1, 1);             stB(0, 0, t + 2);  BAR; WAITL;  MM(0, 1); BAR;  // P6
        LDA(1, 1);             stA(1, 0, t + 3);  BAR; WAITL;  MM(1, 1); BAR;  // P7
        LDB(1, 0);             stB(1, 1, t + 3);  BAR; WAITLV; MM(1, 0); BAR;  // P8
    }
#undef LDA
#undef LDB
#undef MM
#undef BAR
#undef WAITL
#undef WAITLV

    #pragma unroll
    for (int mf = 0; mf < 8; mf++) {
        #pragma unroll
        for (int nf = 0; nf < 4; nf++) {
            #pragma unroll
            for (int j = 0; j < 4; j++) {
                int r = bm + wm * 128 + mf * 16 + (lane >> 4) * 4 + j;
                int c = bn + wn * 64 + nf * 16 + r16;
                float v = acc[mf][nf][j];
                size_t idx = (size_t)r * N + c;
                if (MODE == 0)      { Cb[idx] = f2bf(v + bias[c]); }
                else if (MODE == 1) { Cf[idx] = v + bias[c] + X[idx]; }
                else if (MODE == 2) { Cb[idx] = f2bf(gelu_exact(v)); }
                else                { Cf[idx] = X[idx] + v; }
            }
        }
    }
}

// ---------------------------------------------------------------------------
// Fused causal attention, flash-style (online softmax). Unchanged.
// ---------------------------------------------------------------------------
__global__ __launch_bounds__(256) void attn_kernel(const ushort_t* __restrict__ QKV,
                                                   ushort_t* __restrict__ Ao) {
    __shared__ __align__(16) ushort_t Ks[32 * 136];
    __shared__ __align__(16) ushort_t VsT[128 * 40];
    __shared__ __align__(16) ushort_t Ps[4][16 * 40];
    const int tid  = threadIdx.x;
    const int lane = tid & 63;
    const int wave = tid >> 6;
    const int qtile = blockIdx.x;                 // 0..3
    const int bh = blockIdx.y;                    // local_b * 4 + h
    const int b = bh >> 2;
    const int h = bh & 3;
    const int qb = qtile * 64;
    const int q0 = qb + wave * 16;
    const size_t baseTok = (size_t)b * T_SEQ;

    bf16x8 qf[4];
    {
        const ushort_t* qrow = QKV + (baseTok + q0 + (lane & 15)) * 1536 + h * 128 + (lane >> 4) * 8;
        #pragma unroll
        for (int dc = 0; dc < 4; dc++)
            qf[dc] = *(const bf16x8*)(qrow + dc * 32);
    }

    float m_run[4], l_run[4];
    f32x4 o[8];
    #pragma unroll
    for (int j = 0; j < 4; j++) { m_run[j] = -INFINITY; l_run[j] = 0.0f; }
    #pragma unroll
    for (int nt = 0; nt < 8; nt++) o[nt] = f32x4{0.f, 0.f, 0.f, 0.f};

    const int nchunks = qtile * 2 + 2;
    for (int kc = 0; kc < nchunks; kc++) {
        const int kbase = kc * 32;
        __syncthreads();
        #pragma unroll
        for (int r = 0; r < 2; r++) {
            int li = r * 256 + tid;
            int row = li >> 4;               // 0..31 key within chunk
            int c8 = (li & 15) * 8;          // 0..120 d
            size_t g = (baseTok + kbase + row) * 1536;
            uint4 vk = *(const uint4*)(QKV + g + 512 + h * 128 + c8);
            *(uint4*)(&Ks[row * 136 + c8]) = vk;
            uint4 vv = *(const uint4*)(QKV + g + 1024 + h * 128 + c8);
            ushort_t* pv = (ushort_t*)&vv;
            #pragma unroll
            for (int jj = 0; jj < 8; jj++)
                VsT[(c8 + jj) * 40 + row] = pv[jj];
        }
        __syncthreads();

        if (q0 + 15 >= kbase) {
            f32x4 s0 = {0.f,0.f,0.f,0.f}, s1 = {0.f,0.f,0.f,0.f};
            #pragma unroll
            for (int dc = 0; dc < 4; dc++) {
                bf16x8 kf0 = *(const bf16x8*)(&Ks[(lane & 15) * 136 + dc * 32 + (lane >> 4) * 8]);
                bf16x8 kf1 = *(const bf16x8*)(&Ks[(16 + (lane & 15)) * 136 + dc * 32 + (lane >> 4) * 8]);
                s0 = __builtin_amdgcn_mfma_f32_16x16x32_bf16(qf[dc], kf0, s0, 0, 0, 0);
                s1 = __builtin_amdgcn_mfma_f32_16x16x32_bf16(qf[dc], kf1, s1, 0, 0, 0);
            }
            const int key0 = kbase + (lane & 15);
            const int key1 = key0 + 16;
            float p0[4], p1[4], alpha[4];
            #pragma unroll
            for (int j = 0; j < 4; j++) {
                int qrow = q0 + (lane >> 4) * 4 + j;
                float sv0 = (key0 <= qrow) ? s0[j] * SM_SCALE : -INFINITY;
                float sv1 = (key1 <= qrow) ? s1[j] * SM_SCALE : -INFINITY;
                float mx = fmaxf(sv0, sv1);
                #pragma unroll
                for (int d = 1; d < 16; d <<= 1) mx = fmaxf(mx, __shfl_xor(mx, d));
                float mnew = fmaxf(m_run[j], mx);
                float aa = expf(m_run[j] - mnew);
                p0[j] = expf(sv0 - mnew);
                p1[j] = expf(sv1 - mnew);
                float rs = p0[j] + p1[j];
                #pragma unroll
                for (int d = 1; d < 16; d <<= 1) rs += __shfl_xor(rs, d);
                l_run[j] = l_run[j] * aa + rs;
                m_run[j] = mnew;
                alpha[j] = aa;
            }
            #pragma unroll
            for (int nt = 0; nt < 8; nt++)
                #pragma unroll
                for (int j = 0; j < 4; j++) o[nt][j] *= alpha[j];
            #pragma unroll
            for (int j = 0; j < 4; j++) {
                int rloc = (lane >> 4) * 4 + j;
                Ps[wave][rloc * 40 + (lane & 15)]      = f2bf(p0[j]);
                Ps[wave][rloc * 40 + 16 + (lane & 15)] = f2bf(p1[j]);
            }
            bf16x8 pa = *(const bf16x8*)(&Ps[wave][(lane & 15) * 40 + (lane >> 4) * 8]);
            #pragma unroll
            for (int nt = 0; nt < 8; nt++) {
                bf16x8 vf = *(const bf16x8*)(&VsT[(nt * 16 + (lane & 15)) * 40 + (lane >> 4) * 8]);
                o[nt] = __builtin_amdgcn_mfma_f32_16x16x32_bf16(pa, vf, o[nt], 0, 0, 0);
            }
        }
    }

    #pragma unroll
    for (int j = 0; j < 4; j++) {
        float inv = 1.0f / l_run[j];
        size_t row = baseTok + q0 + (lane >> 4) * 4 + j;
        #pragma unroll
        for (int nt = 0; nt < 8; nt++)
            Ao[row * 512 + h * 128 + nt * 16 + (lane & 15)] = f2bf(o[nt][j] * inv);
    }
}

// ---------------------------------------------------------------------------
extern "C" void kernel_launch(void* const* d_in, const int* in_sizes, int n_in,
                              void* d_out, int out_size, void* d_ws, size_t ws_size,
                              hipStream_t stream) {
    const float* x     = (const float*)d_in[0];
    const float* Wq    = (const float*)d_in[1];
    const float* Wk    = (const float*)d_in[2];
    const float* bk    = (const float*)d_in[3];
    const float* Wv    = (const float*)d_in[4];
    const float* Wproj = (const float*)d_in[5];
    const float* bproj = (const float*)d_in[6];
    const float* w1    = (const float*)d_in[7];
    const float* w2    = (const float*)d_in[8];
    const float* Wi    = (const float*)d_in[9];
    const float* Wo    = (const float*)d_in[10];
    float* out = (float*)d_out;   // also serves as the f32 residual/z/x2 buffer
    (void)in_sizes; (void)n_in; (void)out_size;

    char* ws = (char*)d_ws;
    size_t off = 0;
    auto alloc = [&](size_t bytes) -> void* {
        void* p = ws + off;
        off += (bytes + 255) & ~(size_t)255;
        return p;
    };
    // ---- persistent weights (prepped once per call) ----
    ushort_t* WqkvT    = (ushort_t*)alloc((size_t)1536 * 512 * 2);
    float*    bias1536 = (float*)   alloc((size_t)1536 * 4);
    ushort_t* WprojT   = (ushort_t*)alloc((size_t)512 * 512 * 2);
    ushort_t* WiT      = (ushort_t*)alloc((size_t)4096 * 512 * 2);
    ushort_t* WoT2     = (ushort_t*)alloc((size_t)512 * 4096 * 2);
    const size_t weightBytes = off;

    // ---- choose batch-chunk count so scratch fits ws_size ----
    int nchunks = 1;
    while (nchunks < 64) {
        size_t Mc = (size_t)TOKENS / nchunks;
        size_t need = weightBytes + Mc * 512 * 2 + Mc * 4096 * 2 + 4096;
        if (need <= ws_size) break;
        nchunks *= 2;
    }
    const size_t Mc = (size_t)TOKENS / nchunks;          // tokens per chunk
    const int    nbChunk = B_BATCH / nchunks;            // batches per chunk

    ushort_t* hb  = (ushort_t*)alloc(Mc * 512 * 2);      // h -> attn out -> x2 bf16 (time-shared)
    ushort_t* big = (ushort_t*)alloc(Mc * 4096 * 2);     // qkv (1536 wide) -> hmid (4096 wide)

    // ---- weight prep ----
    prep_qkv <<<(1536 * 512 + 255) / 256, 256, 0, stream>>>(Wq, Wk, Wv, WqkvT);
    prep_bias<<<6, 256, 0, stream>>>(bk, bias1536);
    prep_proj<<<1024, 256, 0, stream>>>(Wproj, WprojT);
    prep_wi  <<<8192, 256, 0, stream>>>(Wi, WiT);
    prep_wo  <<<8192, 256, 0, stream>>>(Wo, WoT2);

    for (int ck = 0; ck < nchunks; ck++) {
        const size_t t0 = (size_t)ck * Mc;
        const float* xC   = x + t0 * 512;
        float*       zC   = out + t0 * 512;
        const int    Mi   = (int)Mc;
        const int    mt   = Mi / 256;                    // 256-row M-tiles

        // h = rmsnorm(x, w1) -> hb (bf16)
        rmsnorm_kernel<0><<<Mi / 4, 256, 0, stream>>>(xC, w1, hb, nullptr);
        // QKV = h @ WqkvT^T + bias -> big (bf16, width 1536)
        gemm256<0><<<mt * 6, 512, 0, stream>>>(
            hb, WqkvT, nullptr, big, bias1536, nullptr, 1536, 512);
        // attention -> hb (bf16, width 512)
        attn_kernel<<<dim3(T_SEQ / 64, nbChunk * H_HEADS), 256, 0, stream>>>(big, hb);
        // z = x + attn @ Wproj + bproj -> zC (f32, lives in d_out)
        gemm256<1><<<mt * 2, 512, 0, stream>>>(
            hb, WprojT, zC, nullptr, bproj, xC, 512, 512);
        // x2 = rmsnorm(z, w2): bf16 -> hb, f32 in-place -> zC
        rmsnorm_kernel<1><<<Mi / 4, 256, 0, stream>>>(zC, w2, hb, zC);
        // hmid = gelu(x2 @ WiT^T), both branches as N=4096 -> big
        gemm256<2><<<mt * 16, 512, 0, stream>>>(
            hb, WiT, nullptr, big, nullptr, nullptr, 4096, 512);
        // out = x2 + hmid @ WoT2^T   (0.5 folded into WoT2, K=4096)
        gemm256<3><<<mt * 2, 512, 0, stream>>>(
            big, WoT2, zC, nullptr, nullptr, zC, 512, 4096);
    }
}